// Round 18
// baseline (2026.815 us; speedup 1.0000x reference)
//
#include <hip/hip_runtime.h>

// MultiLayerLSTM: B=256, T=1024, V=27, E=64, H=128 (4H=512)
// Round 18: round-17 design with preprocessor fix (U##0.x lexed 0.x as one
// pp-number -> invalid paste; now (U##0).x).
//   Batch-pair blocks: each block owns TWO batch elements (same weights,
//   2x FMA fills the serial-chain idle) -> layer needs 128 blocks -> fused
//   dispatch {128x l1(c)} + {128x l0(c+1)} = 256 blocks = 1/CU: layers run
//   concurrently on different CUs. Step bodies = r11/r16-verified math.
// Phases: P0 table; l0_2b(0); gemm(0); {fused2; gemm; proj}x(NC-1); l1_2b; proj.

#define B_  256
#define T_  1024
#define V_  27
#define E_  64
#define H_  128
#define G4  512     // 4*H
#define TPITCH 528  // 4*132 padded table pitch per vocab entry

typedef float v2f __attribute__((ext_vector_type(2)));

__device__ __forceinline__ v2f mkv2(float a, float b) { v2f r; r.x = a; r.y = b; return r; }

template <int CTRL>
__device__ __forceinline__ float dppmov(float v) {
    return __int_as_float(__builtin_amdgcn_update_dpp(
               0, __float_as_int(v), CTRL, 0xF, 0xF, true));
}
__device__ __forceinline__ float qsum(float v) {
    v += dppmov<0xB1>(v);   // quad_perm [1,0,3,2]
    v += dppmov<0x4E>(v);   // quad_perm [2,3,0,1]
    return v;
}
__device__ __forceinline__ float tanh_fast(float y) {
    const float t = __expf(2.f * y);             // inf-safe: tanh(+big)=1
    return fmaf(-2.f, __builtin_amdgcn_rcpf(t + 1.f), 1.f);
}

#define REPEAT16(M) M(0) M(1) M(2) M(3) M(4) M(5) M(6) M(7) \
                    M(8) M(9) M(10) M(11) M(12) M(13) M(14) M(15)

#define DECLW(K) v2f wf##K, wi##K, wg##K, wo##K;
#define LOADW(K) { const float* r0 = wmat + (size_t)(kb + 2*(K)) * G4; \
                   wf##K = mkv2(r0[p],          r0[G4 + p]); \
                   wi##K = mkv2(r0[H_ + p],     r0[G4 + H_ + p]); \
                   wg##K = mkv2(r0[2*H_ + p],   r0[G4 + 2*H_ + p]); \
                   wo##K = mkv2(r0[3*H_ + p],   r0[G4 + 3*H_ + p]); }
#define PINW(K) asm("" : "+v"(wf##K), "+v"(wi##K), "+v"(wg##K), "+v"(wo##K));
#define FMAP2(K, HA, HB, SF, SI, SG, SO) { const v2f h2 = mkv2(HA, HB); \
    SF = __builtin_elementwise_fma(h2, wf##K, SF); \
    SI = __builtin_elementwise_fma(h2, wi##K, SI); \
    SG = __builtin_elementwise_fma(h2, wg##K, SG); \
    SO = __builtin_elementwise_fma(h2, wo##K, SO); }

#define FMABODY2(U, SF, SI, SG, SO) \
    FMAP2(0,  (U##0).x, (U##0).y, SF, SI, SG, SO) FMAP2(1,  (U##0).z, (U##0).w, SF, SI, SG, SO) \
    FMAP2(2,  (U##1).x, (U##1).y, SF, SI, SG, SO) FMAP2(3,  (U##1).z, (U##1).w, SF, SI, SG, SO) \
    FMAP2(4,  (U##2).x, (U##2).y, SF, SI, SG, SO) FMAP2(5,  (U##2).z, (U##2).w, SF, SI, SG, SO) \
    FMAP2(6,  (U##3).x, (U##3).y, SF, SI, SG, SO) FMAP2(7,  (U##3).z, (U##3).w, SF, SI, SG, SO) \
    FMAP2(8,  (U##4).x, (U##4).y, SF, SI, SG, SO) FMAP2(9,  (U##4).z, (U##4).w, SF, SI, SG, SO) \
    FMAP2(10, (U##5).x, (U##5).y, SF, SI, SG, SO) FMAP2(11, (U##5).z, (U##5).w, SF, SI, SG, SO) \
    FMAP2(12, (U##6).x, (U##6).y, SF, SI, SG, SO) FMAP2(13, (U##6).z, (U##6).w, SF, SI, SG, SO) \
    FMAP2(14, (U##7).x, (U##7).y, SF, SI, SG, SO) FMAP2(15, (U##7).z, (U##7).w, SF, SI, SG, SO)

// ---------------- P0: token table, layout [v][4][132] ----------------
__global__ __launch_bounds__(G4)
void build_table0(const float* __restrict__ emb,
                  const float* __restrict__ wx0,
                  const float* __restrict__ b0,
                  float* __restrict__ table0)
{
    const int v = blockIdx.x;        // 0..26
    const int j = threadIdx.x;       // col 0..511
    __shared__ float e[E_];
    if (j < E_) e[j] = emb[v * E_ + j];
    __syncthreads();
    float s = b0[j];
#pragma unroll 8
    for (int k = 0; k < E_; ++k) s = fmaf(e[k], wx0[k * G4 + j], s);
    const int r = j & (H_ - 1), gate = j >> 7;
    table0[v * TPITCH + gate * 132 + r] = s;
}

// ---------------- 2-batch layer-0 body (row x k-quarter) ----------------
__device__ __forceinline__ void l0_body2(
    const int j, const int bb,
    const int* __restrict__ x, const float* __restrict__ table0,
    const float* __restrict__ wh0,
    float* __restrict__ h0st, float* __restrict__ c0st,
    float* __restrict__ h0buf, int t0, int TC,
    float (*hPA)[4][36], float (*hPB)[4][36])
{
    const int p = j >> 2;             // row 0..127
    const int e = j & 3;              // k-quarter
    const int kb = 32 * e;

    const float* wmat = wh0;
    REPEAT16(DECLW)
    REPEAT16(LOADW)
    if (j < H_) {
        hPA[0][j >> 5][j & 31] = h0st[(size_t)bb * H_ + j];
        hPB[0][j >> 5][j & 31] = h0st[(size_t)(bb + 1) * H_ + j];
    }
    float cA = c0st[(size_t)bb * H_ + p];
    float cB = c0st[(size_t)(bb + 1) * H_ + p];
    float hhA = 0.f, hhB = 0.f;
    __syncthreads();

    const int* xbA = x + (size_t)bb * T_ + t0;
    const int* xbB = x + (size_t)(bb + 1) * T_ + t0;
    float* hobA = h0buf + (size_t)bb * TC * H_;
    float* hobB = h0buf + (size_t)(bb + 1) * TC * H_;
    const float A = (e == 2) ? 2.f : 1.f;   // tanh for g-gate, sigmoid else
    const int toff = e * 132 + p;

    float tvA = table0[xbA[0] * TPITCH + toff];
    float tvB = table0[xbB[0] * TPITCH + toff];
    for (int t = 0; t < TC; ++t) {
        REPEAT16(PINW)
        const int idxnA = (t + 1 < TC) ? xbA[t + 1] : 0;
        const int idxnB = (t + 1 < TC) ? xbB[t + 1] : 0;

        const float4* ha4 = reinterpret_cast<const float4*>(&hPA[t & 1][e][0]);
        const float4 uA0 = ha4[0], uA1 = ha4[1], uA2 = ha4[2], uA3 = ha4[3],
                     uA4 = ha4[4], uA5 = ha4[5], uA6 = ha4[6], uA7 = ha4[7];
        v2f sfA = mkv2(0.f, 0.f), siA = sfA, sgA = sfA, soA = sfA;
        FMABODY2(uA, sfA, siA, sgA, soA)

        const float4* hb4 = reinterpret_cast<const float4*>(&hPB[t & 1][e][0]);
        const float4 uB0 = hb4[0], uB1 = hb4[1], uB2 = hb4[2], uB3 = hb4[3],
                     uB4 = hb4[4], uB5 = hb4[5], uB6 = hb4[6], uB7 = hb4[7];
        v2f sfB = mkv2(0.f, 0.f), siB = sfB, sgB = sfB, soB = sfB;
        FMABODY2(uB, sfB, siB, sgB, soB)

        const float rfA = qsum(sfA.x + sfA.y);
        const float riA = qsum(siA.x + siA.y);
        const float rgA = qsum(sgA.x + sgA.y);
        const float roA = qsum(soA.x + soA.y);
        const float rfB = qsum(sfB.x + sfB.y);
        const float riB = qsum(siB.x + siB.y);
        const float rgB = qsum(sgB.x + sgB.y);
        const float roB = qsum(soB.x + soB.y);

        float valA = (e == 0) ? rfA : (e == 1) ? riA : (e == 2) ? rgA : roA;
        float valB = (e == 0) ? rfB : (e == 1) ? riB : (e == 2) ? rgB : roB;
        valA += tvA; valB += tvB;
        const float actA = fmaf(-A, __builtin_amdgcn_rcpf(__expf(A * valA) + 1.f), 1.f);
        const float actB = fmaf(-A, __builtin_amdgcn_rcpf(__expf(A * valB) + 1.f), 1.f);

        const float ivA = dppmov<0x39>(actA);
        const float gvA = dppmov<0x4E>(actA);
        const float ovA = dppmov<0x93>(actA);
        cA  = fmaf(actA, cA, ivA * gvA);
        hhA = tanh_fast(cA) * ovA;
        const float ivB = dppmov<0x39>(actB);
        const float gvB = dppmov<0x4E>(actB);
        const float ovB = dppmov<0x93>(actB);
        cB  = fmaf(actB, cB, ivB * gvB);
        hhB = tanh_fast(cB) * ovB;

        if (e == 0) {
            hPA[(t + 1) & 1][p >> 5][p & 31] = hhA;
            hPB[(t + 1) & 1][p >> 5][p & 31] = hhB;
            hobA[(size_t)t * H_ + p] = hhA;
            hobB[(size_t)t * H_ + p] = hhB;
        }
        tvA = table0[idxnA * TPITCH + toff];
        tvB = table0[idxnB * TPITCH + toff];
        __syncthreads();
    }
    if (e == 0) {
        h0st[(size_t)bb * H_ + p] = hhA;       c0st[(size_t)bb * H_ + p] = cA;
        h0st[(size_t)(bb + 1) * H_ + p] = hhB; c0st[(size_t)(bb + 1) * H_ + p] = cB;
    }
}

// ---------------- 2-batch layer-1 body (row x k-quarter) ----------------
__device__ __forceinline__ void l1_body2(
    const int j, const int bb,
    const float* __restrict__ xg1, const float* __restrict__ wh1,
    float* __restrict__ h1st, float* __restrict__ c1st,
    float* __restrict__ h1buf, int TC,
    float (*hPA)[4][36], float (*hPB)[4][36])
{
    const int p = j >> 2;
    const int e = j & 3;
    const int kb = 32 * e;

    const float* wmat = wh1;
    REPEAT16(DECLW)
    REPEAT16(LOADW)
    if (j < H_) {
        hPA[0][j >> 5][j & 31] = h1st[(size_t)bb * H_ + j];
        hPB[0][j >> 5][j & 31] = h1st[(size_t)(bb + 1) * H_ + j];
    }
    float cA = c1st[(size_t)bb * H_ + p];
    float cB = c1st[(size_t)(bb + 1) * H_ + p];
    float hhA = 0.f, hhB = 0.f;
    __syncthreads();

    const float* xgA = xg1 + (size_t)bb * TC * G4;
    const float* xgB = xg1 + (size_t)(bb + 1) * TC * G4;
    float* hobA = h1buf + (size_t)bb * TC * H_;
    float* hobB = h1buf + (size_t)(bb + 1) * TC * H_;
    const float A = (e == 2) ? 2.f : 1.f;
    const int xcol = e * H_ + p;

    float xvA = xgA[xcol];
    float xvB = xgB[xcol];
    for (int t = 0; t < TC; ++t) {
        REPEAT16(PINW)
        const float xvnA = (t + 1 < TC) ? xgA[(size_t)(t + 1) * G4 + xcol] : 0.f;
        const float xvnB = (t + 1 < TC) ? xgB[(size_t)(t + 1) * G4 + xcol] : 0.f;

        const float4* ha4 = reinterpret_cast<const float4*>(&hPA[t & 1][e][0]);
        const float4 uA0 = ha4[0], uA1 = ha4[1], uA2 = ha4[2], uA3 = ha4[3],
                     uA4 = ha4[4], uA5 = ha4[5], uA6 = ha4[6], uA7 = ha4[7];
        v2f sfA = mkv2(0.f, 0.f), siA = sfA, sgA = sfA, soA = sfA;
        FMABODY2(uA, sfA, siA, sgA, soA)

        const float4* hb4 = reinterpret_cast<const float4*>(&hPB[t & 1][e][0]);
        const float4 uB0 = hb4[0], uB1 = hb4[1], uB2 = hb4[2], uB3 = hb4[3],
                     uB4 = hb4[4], uB5 = hb4[5], uB6 = hb4[6], uB7 = hb4[7];
        v2f sfB = mkv2(0.f, 0.f), siB = sfB, sgB = sfB, soB = sfB;
        FMABODY2(uB, sfB, siB, sgB, soB)

        const float rfA = qsum(sfA.x + sfA.y);
        const float riA = qsum(siA.x + siA.y);
        const float rgA = qsum(sgA.x + sgA.y);
        const float roA = qsum(soA.x + soA.y);
        const float rfB = qsum(sfB.x + sfB.y);
        const float riB = qsum(siB.x + siB.y);
        const float rgB = qsum(sgB.x + sgB.y);
        const float roB = qsum(soB.x + soB.y);

        float valA = (e == 0) ? rfA : (e == 1) ? riA : (e == 2) ? rgA : roA;
        float valB = (e == 0) ? rfB : (e == 1) ? riB : (e == 2) ? rgB : roB;
        valA += xvA; valB += xvB;                  // xg1 already includes b1
        const float actA = fmaf(-A, __builtin_amdgcn_rcpf(__expf(A * valA) + 1.f), 1.f);
        const float actB = fmaf(-A, __builtin_amdgcn_rcpf(__expf(A * valB) + 1.f), 1.f);

        const float ivA = dppmov<0x39>(actA);
        const float gvA = dppmov<0x4E>(actA);
        const float ovA = dppmov<0x93>(actA);
        cA  = fmaf(actA, cA, ivA * gvA);
        hhA = tanh_fast(cA) * ovA;
        const float ivB = dppmov<0x39>(actB);
        const float gvB = dppmov<0x4E>(actB);
        const float ovB = dppmov<0x93>(actB);
        cB  = fmaf(actB, cB, ivB * gvB);
        hhB = tanh_fast(cB) * ovB;

        if (e == 0) {
            hPA[(t + 1) & 1][p >> 5][p & 31] = hhA;
            hPB[(t + 1) & 1][p >> 5][p & 31] = hhB;
            hobA[(size_t)t * H_ + p] = hhA;
            hobB[(size_t)t * H_ + p] = hhB;
        }
        xvA = xvnA; xvB = xvnB;
        __syncthreads();
    }
    if (e == 0) {
        h1st[(size_t)bb * H_ + p] = hhA;       c1st[(size_t)bb * H_ + p] = cA;
        h1st[(size_t)(bb + 1) * H_ + p] = hhB; c1st[(size_t)(bb + 1) * H_ + p] = cB;
    }
}

// ---------------- standalone 2-batch kernels (128 blocks) ----------------
__global__ __launch_bounds__(512, 2)
void lstm_l0_2b(const int* __restrict__ x, const float* __restrict__ table0,
                const float* __restrict__ wh0,
                float* __restrict__ h0st, float* __restrict__ c0st,
                float* __restrict__ h0buf, int t0, int TC)
{
    __shared__ __align__(16) float hPA[2][4][36];
    __shared__ __align__(16) float hPB[2][4][36];
    l0_body2(threadIdx.x, 2 * blockIdx.x, x, table0, wh0, h0st, c0st, h0buf,
             t0, TC, hPA, hPB);
}

__global__ __launch_bounds__(512, 2)
void lstm_l1_2b(const float* __restrict__ xg1, const float* __restrict__ wh1,
                float* __restrict__ h1st, float* __restrict__ c1st,
                float* __restrict__ h1buf, int TC)
{
    __shared__ __align__(16) float hPA[2][4][36];
    __shared__ __align__(16) float hPB[2][4][36];
    l1_body2(threadIdx.x, 2 * blockIdx.x, xg1, wh1, h1st, c1st, h1buf, TC,
             hPA, hPB);
}

// ---------------- fused: 128 blocks l1(c) + 128 blocks l0(c+1) ----------------
__global__ __launch_bounds__(512, 2)
void lstm_fused2(const int* __restrict__ x, const float* __restrict__ table0,
                 const float* __restrict__ wh0,
                 const float* __restrict__ xg1, const float* __restrict__ wh1,
                 float* __restrict__ h0st, float* __restrict__ c0st,
                 float* __restrict__ h0buf,
                 float* __restrict__ h1st, float* __restrict__ c1st,
                 float* __restrict__ h1buf,
                 int t0_l0, int TC)
{
    __shared__ __align__(16) float hPA[2][4][36];
    __shared__ __align__(16) float hPB[2][4][36];
    const int bid = blockIdx.x;
    if (bid < B_ / 2) {
        l1_body2(threadIdx.x, 2 * bid, xg1, wh1, h1st, c1st, h1buf, TC,
                 hPA, hPB);
    } else {
        l0_body2(threadIdx.x, 2 * (bid - B_ / 2), x, table0, wh0,
                 h0st, c0st, h0buf, t0_l0, TC, hPA, hPB);
    }
}

// ---------------- P2: xg1 = h0 @ wx1 + b1 ----------------
__global__ __launch_bounds__(G4, 2)
void gemm_xg1(const float* __restrict__ h0buf,
              const float* __restrict__ wx1,
              const float* __restrict__ b1,
              float* __restrict__ xg1)
{
    const int j  = threadIdx.x;
    const size_t m0 = (size_t)blockIdx.x * 64;
    const int c  = j & 127;          // cols c, c+128, c+256, c+384
    const int rg = j >> 7;           // rows rg*16 .. rg*16+15

    __shared__ __align__(16) float aT[64 * 132];   // row-major [r][k], pad 132

#pragma unroll
    for (int i = 0; i < 4; ++i) {
        const int e  = i * G4 + j;       // float4 index 0..2047
        const int r  = e >> 5;           // 32 float4 per row
        const int k4 = e & 31;
        const float4 v = *reinterpret_cast<const float4*>(&h0buf[(m0 + r) * H_ + k4 * 4]);
        *reinterpret_cast<float4*>(&aT[r * 132 + k4 * 4]) = v;
    }
    __syncthreads();

    float acc[4][16];
#pragma unroll
    for (int cc = 0; cc < 4; ++cc)
#pragma unroll
        for (int rr = 0; rr < 16; ++rr) acc[cc][rr] = 0.f;

    for (int k4 = 0; k4 < 32; ++k4) {
        float bv[4][4];   // [kk][cc]
#pragma unroll
        for (int kk = 0; kk < 4; ++kk)
#pragma unroll
            for (int cc = 0; cc < 4; ++cc)
                bv[kk][cc] = wx1[(size_t)(k4 * 4 + kk) * G4 + cc * 128 + c];
#pragma unroll
        for (int rr = 0; rr < 16; ++rr) {
            const float4 av = *reinterpret_cast<const float4*>(&aT[(rg * 16 + rr) * 132 + k4 * 4]);
#pragma unroll
            for (int cc = 0; cc < 4; ++cc) {
                acc[cc][rr] = fmaf(av.x, bv[0][cc], acc[cc][rr]);
                acc[cc][rr] = fmaf(av.y, bv[1][cc], acc[cc][rr]);
                acc[cc][rr] = fmaf(av.z, bv[2][cc], acc[cc][rr]);
                acc[cc][rr] = fmaf(av.w, bv[3][cc], acc[cc][rr]);
            }
        }
    }

    float b1v[4];
#pragma unroll
    for (int cc = 0; cc < 4; ++cc) b1v[cc] = b1[cc * 128 + c];
#pragma unroll
    for (int rr = 0; rr < 16; ++rr) {
        const size_t row = m0 + rg * 16 + rr;
#pragma unroll
        for (int cc = 0; cc < 4; ++cc)
            xg1[row * G4 + cc * 128 + c] = acc[cc][rr] + b1v[cc];
    }
}

// ---------------- P4: y = h1 @ why + by ----------------
__global__ __launch_bounds__(256)
void proj_y(const float* __restrict__ h1buf,
            const float* __restrict__ why,
            const float* __restrict__ by,
            float* __restrict__ out,
            int t0, int TC)
{
    const int tid = threadIdx.x;
    const int b   = blockIdx.x;

    __shared__ __align__(16) float whyS[V_][H_];   // [v][k], broadcast-read
    __shared__ float byS[V_];
    __shared__ float yS[256][29];                  // pad 29: conflict-free stage

    for (int e = tid; e < V_ * H_; e += 256) {
        const int v = e / H_, k = e - v * H_;
        whyS[v][k] = why[k * V_ + v];
    }
    if (tid < V_) byS[tid] = by[tid];
    __syncthreads();

    const float* hb  = h1buf + (size_t)b * TC * H_;
    float* outb      = out + ((size_t)b * T_ + t0) * V_;

    for (int tt0 = 0; tt0 < TC; tt0 += 256) {
        const int tt = tt0 + tid;
        if (tt < TC) {
            float acc[V_];
#pragma unroll
            for (int v = 0; v < V_; ++v) acc[v] = byS[v];
            const float4* hr = reinterpret_cast<const float4*>(hb + (size_t)tt * H_);
#pragma unroll 4
            for (int k4 = 0; k4 < 32; ++k4) {
                const float4 hv = hr[k4];
#pragma unroll
                for (int v = 0; v < V_; ++v) {
                    const float4 wv = *reinterpret_cast<const float4*>(&whyS[v][k4 * 4]);
                    acc[v] = fmaf(hv.x, wv.x,
                             fmaf(hv.y, wv.y,
                             fmaf(hv.z, wv.z,
                             fmaf(hv.w, wv.w, acc[v]))));
                }
            }
#pragma unroll
            for (int v = 0; v < V_; ++v) yS[tid][v] = acc[v];
        }
        __syncthreads();
        const int nrow = (TC - tt0 < 256) ? (TC - tt0) : 256;
        const int n = nrow * V_;
        float* od = outb + (size_t)tt0 * V_;
        for (int i = tid; i < n; i += 256) {
            const int r = i / V_, v = i - r * V_;
            od[i] = yS[r][v];
        }
        __syncthreads();
    }
}

// ---------------- fallback: streaming kernel (uses [v][4][132] table) ----------------
__global__ __launch_bounds__(G4, 1)
void lstm_persist(const int* __restrict__ x,
                  const float* __restrict__ table0,
                  const float* __restrict__ wh0,
                  const float* __restrict__ wx1,
                  const float* __restrict__ wh1,
                  const float* __restrict__ b1,
                  const float* __restrict__ why,
                  const float* __restrict__ by,
                  float* __restrict__ out)
{
    const int j  = threadIdx.x;
    const int bb = blockIdx.x * 2;

    __shared__ float h0s[2][H_], c0s[2][H_], h1s[2][H_], c1s[2][H_];
    __shared__ float hcat[2][2 * H_];
    __shared__ float g0s[2][G4], g1s[2][G4];
    __shared__ float whyS[H_ * V_];
    __shared__ float b1S[G4];
    __shared__ float byS[V_];
    __shared__ float pb[2][V_][8];

    for (int i = j; i < H_ * V_; i += G4) whyS[i] = why[i];
    b1S[j] = b1[j];
    if (j < V_) byS[j] = by[j];
    if (j < H_) {
        h0s[0][j] = 0.f; h0s[1][j] = 0.f; c0s[0][j] = 0.f; c0s[1][j] = 0.f;
        h1s[0][j] = 0.f; h1s[1][j] = 0.f; c1s[0][j] = 0.f; c1s[1][j] = 0.f;
    }
    __syncthreads();

    const int* xA = x + (size_t)(bb + 0) * T_;
    const int* xB = x + (size_t)(bb + 1) * T_;
    float* outA = out + (size_t)(bb + 0) * T_ * V_;
    float* outB = out + (size_t)(bb + 1) * T_ * V_;

    const int tix = (j >> 7) * 132 + (j & (H_ - 1));

    for (int t = 0; t < T_; ++t) {
        const int ia = xA[t];
        const int ib = xB[t];
        float aA = table0[ia * TPITCH + tix];
        float aB = table0[ib * TPITCH + tix];
#pragma unroll 8
        for (int k = 0; k < H_; ++k) {
            const float w = wh0[k * G4 + j];
            aA += h0s[0][k] * w;
            aB += h0s[1][k] * w;
        }
        g0s[0][j] = aA; g0s[1][j] = aB;
        __syncthreads();

        if (j < 2 * H_) {
            const int gi = j >> 7, r = j & (H_ - 1);
            const float f  = 1.f / (1.f + expf(-g0s[gi][r]));
            const float i_ = 1.f / (1.f + expf(-g0s[gi][H_ + r]));
            const float g  = tanhf(g0s[gi][2 * H_ + r]);
            const float o  = 1.f / (1.f + expf(-g0s[gi][3 * H_ + r]));
            const float c  = f * c0s[gi][r] + i_ * g;
            c0s[gi][r] = c;
            const float h = tanhf(c) * o;
            h0s[gi][r] = h;
            hcat[gi][r] = h;
            hcat[gi][H_ + r] = h1s[gi][r];
        }
        __syncthreads();

        float bA = b1S[j];
        float bB = bA;
#pragma unroll 8
        for (int k = 0; k < H_; ++k) {
            const float w = wx1[k * G4 + j];
            bA += hcat[0][k] * w;
            bB += hcat[1][k] * w;
        }
#pragma unroll 8
        for (int k = 0; k < H_; ++k) {
            const float w = wh1[k * G4 + j];
            bA += hcat[0][H_ + k] * w;
            bB += hcat[1][H_ + k] * w;
        }
        g1s[0][j] = bA; g1s[1][j] = bB;
        __syncthreads();

        if (j < 2 * H_) {
            const int gi = j >> 7, r = j & (H_ - 1);
            const float f  = 1.f / (1.f + expf(-g1s[gi][r]));
            const float i_ = 1.f / (1.f + expf(-g1s[gi][H_ + r]));
            const float g  = tanhf(g1s[gi][2 * H_ + r]);
            const float o  = 1.f / (1.f + expf(-g1s[gi][3 * H_ + r]));
            const float c  = f * c1s[gi][r] + i_ * g;
            c1s[gi][r] = c;
            h1s[gi][r] = tanhf(c) * o;
        }
        __syncthreads();

        if (j < 2 * V_ * 8) {
            int qq = j;
            const int gi = (qq >= V_ * 8) ? 1 : 0;
            qq -= gi * V_ * 8;
            const int v = qq >> 3, kk = qq & 7;
            float pv = 0.f;
#pragma unroll
            for (int k = kk * 16; k < kk * 16 + 16; ++k)
                pv += h1s[gi][k] * whyS[k * V_ + v];
            pb[gi][v][kk] = pv;
        }
        __syncthreads();

        if (j < 2 * V_) {
            const int gi = (j >= V_) ? 1 : 0;
            const int v  = j - gi * V_;
            float sA = byS[v];
#pragma unroll
            for (int qq = 0; qq < 8; ++qq) sA += pb[gi][v][qq];
            (gi ? outB : outA)[t * V_ + v] = sA;
        }
        __syncthreads();
    }
}

// ---------------- host ----------------
extern "C" void kernel_launch(void* const* d_in, const int* in_sizes, int n_in,
                              void* d_out, int out_size, void* d_ws, size_t ws_size,
                              hipStream_t stream)
{
    const int*   x   = (const int*)  d_in[0];
    const float* emb = (const float*)d_in[1];
    const float* wx0 = (const float*)d_in[2];
    const float* wh0 = (const float*)d_in[3];
    const float* b0  = (const float*)d_in[4];
    const float* wx1 = (const float*)d_in[5];
    const float* wh1 = (const float*)d_in[6];
    const float* b1  = (const float*)d_in[7];
    const float* why = (const float*)d_in[8];
    const float* by  = (const float*)d_in[9];
    float* out = (float*)d_out;
    float* wsf = (float*)d_ws;

    const size_t tabF   = (size_t)V_ * TPITCH;   // 14256 floats
    const size_t stateF = (size_t)4 * B_ * H_;   // 131072 floats

    int TC = 0;
    for (int tc = 256; tc >= 32; tc >>= 1) {   // cap 256: NC>=4 for pipelining
        const size_t need = (tabF + stateF + (size_t)B_ * tc * (H_ + G4 + H_)) * 4;
        if (need <= ws_size) { TC = tc; break; }
    }

    float* table0 = wsf;
    build_table0<<<dim3(V_), dim3(G4), 0, stream>>>(emb, wx0, b0, table0);

    if (TC == 0) {
        lstm_persist<<<dim3(B_ / 2), dim3(G4), 0, stream>>>(
            x, table0, wh0, wx1, wh1, b1, why, by, out);
        return;
    }

    float* h0st   = wsf + tabF;
    float* c0st   = h0st + (size_t)B_ * H_;
    float* h1st   = c0st + (size_t)B_ * H_;
    float* c1st   = h1st + (size_t)B_ * H_;
    float* h0buf  = c1st + (size_t)B_ * H_;
    float* xg1buf = h0buf + (size_t)B_ * TC * H_;
    float* h1buf  = xg1buf + (size_t)B_ * TC * G4;

    (void)hipMemsetAsync(h0st, 0, stateF * sizeof(float), stream);

    const int NC = T_ / TC;

    // prologue: l0 chunk 0 (128 blocks, 2 batches each) + its gemm
    lstm_l0_2b<<<dim3(B_ / 2), dim3(512), 0, stream>>>(
        x, table0, wh0, h0st, c0st, h0buf, 0, TC);
    gemm_xg1<<<dim3(4 * TC), dim3(G4), 0, stream>>>(h0buf, wx1, b1, xg1buf);

    // pipelined middle: fused{l1(c) || l0(c+1)}; gemm(c+1); proj(c)
    for (int c = 0; c < NC - 1; ++c) {
        lstm_fused2<<<dim3(B_), dim3(512), 0, stream>>>(
            x, table0, wh0, xg1buf, wh1,
            h0st, c0st, h0buf, h1st, c1st, h1buf,
            (c + 1) * TC, TC);
        gemm_xg1<<<dim3(4 * TC), dim3(G4), 0, stream>>>(h0buf, wx1, b1, xg1buf);
        proj_y<<<dim3(B_), dim3(256), 0, stream>>>(
            h1buf, why, by, out, c * TC, TC);
    }

    // epilogue: last l1 chunk + its projection
    lstm_l1_2b<<<dim3(B_ / 2), dim3(512), 0, stream>>>(
        xg1buf, wh1, h1st, c1st, h1buf, TC);
    proj_y<<<dim3(B_), dim3(256), 0, stream>>>(
        h1buf, why, by, out, (NC - 1) * TC, TC);
}

// Round 19
// 1807.936 us; speedup vs baseline: 1.1211x; 1.1211x over previous
//
#include <hip/hip_runtime.h>

// MultiLayerLSTM: B=256, T=1024, V=27, E=64, H=128 (4H=512)
// Round 19: fused2 middle (r18, 165us/layer-chunk effective) + FULL-WIDTH
// single-batch fill/drain (r16 kernels, 256 blocks) instead of r18's
// half-chip 2-batch prologue/epilogue (~300us each at 128 blocks).
// Schedule: P0 table; l0_1b(0) [256 blk]; gemm(0);
//           {fused2(l1(c)||l0(c+1)); gemm(c+1); proj(c)} x (NC-1);
//           l1_1b(NC-1) [256 blk]; proj(NC-1).

#define B_  256
#define T_  1024
#define V_  27
#define E_  64
#define H_  128
#define G4  512     // 4*H
#define TPITCH 528  // 4*132 padded table pitch per vocab entry

typedef float v2f __attribute__((ext_vector_type(2)));

__device__ __forceinline__ v2f mkv2(float a, float b) { v2f r; r.x = a; r.y = b; return r; }

template <int CTRL>
__device__ __forceinline__ float dppmov(float v) {
    return __int_as_float(__builtin_amdgcn_update_dpp(
               0, __float_as_int(v), CTRL, 0xF, 0xF, true));
}
__device__ __forceinline__ float qsum(float v) {
    v += dppmov<0xB1>(v);   // quad_perm [1,0,3,2]
    v += dppmov<0x4E>(v);   // quad_perm [2,3,0,1]
    return v;
}
__device__ __forceinline__ float tanh_fast(float y) {
    const float t = __expf(2.f * y);             // inf-safe: tanh(+big)=1
    return fmaf(-2.f, __builtin_amdgcn_rcpf(t + 1.f), 1.f);
}

#define REPEAT16(M) M(0) M(1) M(2) M(3) M(4) M(5) M(6) M(7) \
                    M(8) M(9) M(10) M(11) M(12) M(13) M(14) M(15)

#define DECLW(K) v2f wf##K, wi##K, wg##K, wo##K;
#define LOADW(K) { const float* r0 = wmat + (size_t)(kb + 2*(K)) * G4; \
                   wf##K = mkv2(r0[p],          r0[G4 + p]); \
                   wi##K = mkv2(r0[H_ + p],     r0[G4 + H_ + p]); \
                   wg##K = mkv2(r0[2*H_ + p],   r0[G4 + 2*H_ + p]); \
                   wo##K = mkv2(r0[3*H_ + p],   r0[G4 + 3*H_ + p]); }
#define PINW(K) asm("" : "+v"(wf##K), "+v"(wi##K), "+v"(wg##K), "+v"(wo##K));

// single-batch FMA body (r16)
#define FMAP(K, HA, HB) { const v2f h2 = mkv2(HA, HB); \
    sf2 = __builtin_elementwise_fma(h2, wf##K, sf2); \
    si2 = __builtin_elementwise_fma(h2, wi##K, si2); \
    sg2 = __builtin_elementwise_fma(h2, wg##K, sg2); \
    so2 = __builtin_elementwise_fma(h2, wo##K, so2); }
#define FMABODY \
    v2f sf2 = mkv2(0.f, 0.f), si2 = sf2, sg2 = sf2, so2 = sf2; \
    FMAP(0,  v0.x, v0.y) FMAP(1,  v0.z, v0.w) \
    FMAP(2,  v1.x, v1.y) FMAP(3,  v1.z, v1.w) \
    FMAP(4,  v2.x, v2.y) FMAP(5,  v2.z, v2.w) \
    FMAP(6,  v3.x, v3.y) FMAP(7,  v3.z, v3.w) \
    FMAP(8,  v4.x, v4.y) FMAP(9,  v4.z, v4.w) \
    FMAP(10, v5.x, v5.y) FMAP(11, v5.z, v5.w) \
    FMAP(12, v6.x, v6.y) FMAP(13, v6.z, v6.w) \
    FMAP(14, v7.x, v7.y) FMAP(15, v7.z, v7.w)

// 2-batch FMA body (r18)
#define FMAP2(K, HA, HB, SF, SI, SG, SO) { const v2f h2 = mkv2(HA, HB); \
    SF = __builtin_elementwise_fma(h2, wf##K, SF); \
    SI = __builtin_elementwise_fma(h2, wi##K, SI); \
    SG = __builtin_elementwise_fma(h2, wg##K, SG); \
    SO = __builtin_elementwise_fma(h2, wo##K, SO); }
#define FMABODY2(U, SF, SI, SG, SO) \
    FMAP2(0,  (U##0).x, (U##0).y, SF, SI, SG, SO) FMAP2(1,  (U##0).z, (U##0).w, SF, SI, SG, SO) \
    FMAP2(2,  (U##1).x, (U##1).y, SF, SI, SG, SO) FMAP2(3,  (U##1).z, (U##1).w, SF, SI, SG, SO) \
    FMAP2(4,  (U##2).x, (U##2).y, SF, SI, SG, SO) FMAP2(5,  (U##2).z, (U##2).w, SF, SI, SG, SO) \
    FMAP2(6,  (U##3).x, (U##3).y, SF, SI, SG, SO) FMAP2(7,  (U##3).z, (U##3).w, SF, SI, SG, SO) \
    FMAP2(8,  (U##4).x, (U##4).y, SF, SI, SG, SO) FMAP2(9,  (U##4).z, (U##4).w, SF, SI, SG, SO) \
    FMAP2(10, (U##5).x, (U##5).y, SF, SI, SG, SO) FMAP2(11, (U##5).z, (U##5).w, SF, SI, SG, SO) \
    FMAP2(12, (U##6).x, (U##6).y, SF, SI, SG, SO) FMAP2(13, (U##6).z, (U##6).w, SF, SI, SG, SO) \
    FMAP2(14, (U##7).x, (U##7).y, SF, SI, SG, SO) FMAP2(15, (U##7).z, (U##7).w, SF, SI, SG, SO)

// ---------------- P0: token table, layout [v][4][132] ----------------
__global__ __launch_bounds__(G4)
void build_table0(const float* __restrict__ emb,
                  const float* __restrict__ wx0,
                  const float* __restrict__ b0,
                  float* __restrict__ table0)
{
    const int v = blockIdx.x;        // 0..26
    const int j = threadIdx.x;       // col 0..511
    __shared__ float e[E_];
    if (j < E_) e[j] = emb[v * E_ + j];
    __syncthreads();
    float s = b0[j];
#pragma unroll 8
    for (int k = 0; k < E_; ++k) s = fmaf(e[k], wx0[k * G4 + j], s);
    const int r = j & (H_ - 1), gate = j >> 7;
    table0[v * TPITCH + gate * 132 + r] = s;
}

// ---------------- single-batch l0 (r16, 256 blocks): pipeline fill ----------------
__global__ __launch_bounds__(512, 2)
void lstm_l0_1b(const int* __restrict__ x,
                const float* __restrict__ table0,
                const float* __restrict__ wh0,
                float* __restrict__ h0st, float* __restrict__ c0st,
                float* __restrict__ h0buf,
                int t0, int TC)
{
    const int j = threadIdx.x;        // 0..511
    const int p = j >> 2;             // row 0..127
    const int e = j & 3;              // k-quarter
    const int b = blockIdx.x;
    const int kb = 32 * e;

    __shared__ __align__(16) float hP[2][4][36];

    const float* wmat = wh0;
    REPEAT16(DECLW)
    REPEAT16(LOADW)
    if (j < H_) hP[0][j >> 5][j & 31] = h0st[b * H_ + j];
    float c = c0st[b * H_ + p];
    float hh = 0.f;
    __syncthreads();

    const int* xb = x + (size_t)b * T_ + t0;
    float* hob = h0buf + (size_t)b * TC * H_;
    const float A = (e == 2) ? 2.f : 1.f;
    const int toff = e * 132 + p;

    float tv = table0[xb[0] * TPITCH + toff];
    for (int t = 0; t < TC; ++t) {
        REPEAT16(PINW)
        const int idxn = (t + 1 < TC) ? xb[t + 1] : 0;

        const float4* hb4 = reinterpret_cast<const float4*>(&hP[t & 1][e][0]);
        const float4 v0 = hb4[0], v1 = hb4[1], v2 = hb4[2], v3 = hb4[3],
                     v4 = hb4[4], v5 = hb4[5], v6 = hb4[6], v7 = hb4[7];
        FMABODY
        const float sf = qsum(sf2.x + sf2.y);
        const float si = qsum(si2.x + si2.y);
        const float sg = qsum(sg2.x + sg2.y);
        const float so = qsum(so2.x + so2.y);

        float val = (e == 0) ? sf : (e == 1) ? si : (e == 2) ? sg : so;
        val += tv;
        const float tz  = __expf(A * val);
        const float act = fmaf(-A, __builtin_amdgcn_rcpf(tz + 1.f), 1.f);

        const float iv = dppmov<0x39>(act);
        const float gv = dppmov<0x4E>(act);
        const float ov = dppmov<0x93>(act);
        c  = fmaf(act, c, iv * gv);
        hh = tanh_fast(c) * ov;

        if (e == 0) {
            hP[(t + 1) & 1][p >> 5][p & 31] = hh;
            hob[(size_t)t * H_ + p] = hh;
        }
        tv = table0[idxn * TPITCH + toff];
        __syncthreads();
    }
    if (e == 0) { h0st[b * H_ + p] = hh; c0st[b * H_ + p] = c; }
}

// ---------------- single-batch l1 (r16, 256 blocks): pipeline drain ----------------
__global__ __launch_bounds__(512, 2)
void lstm_l1_1b(const float* __restrict__ xg1,
                const float* __restrict__ wh1,
                float* __restrict__ h1st, float* __restrict__ c1st,
                float* __restrict__ h1buf,
                int TC)
{
    const int j = threadIdx.x;
    const int p = j >> 2;
    const int e = j & 3;
    const int b = blockIdx.x;
    const int kb = 32 * e;

    __shared__ __align__(16) float hP[2][4][36];

    const float* wmat = wh1;
    REPEAT16(DECLW)
    REPEAT16(LOADW)
    if (j < H_) hP[0][j >> 5][j & 31] = h1st[b * H_ + j];
    float c = c1st[b * H_ + p];
    float hh = 0.f;
    __syncthreads();

    const float* xgb = xg1 + (size_t)b * TC * G4;
    float* hob = h1buf + (size_t)b * TC * H_;
    const float A = (e == 2) ? 2.f : 1.f;
    const int xcol = e * H_ + p;

    float xv = xgb[xcol];
    for (int t = 0; t < TC; ++t) {
        REPEAT16(PINW)
        const float xvn = (t + 1 < TC) ? xgb[(size_t)(t + 1) * G4 + xcol] : 0.f;

        const float4* hb4 = reinterpret_cast<const float4*>(&hP[t & 1][e][0]);
        const float4 v0 = hb4[0], v1 = hb4[1], v2 = hb4[2], v3 = hb4[3],
                     v4 = hb4[4], v5 = hb4[5], v6 = hb4[6], v7 = hb4[7];
        FMABODY
        const float sf = qsum(sf2.x + sf2.y);
        const float si = qsum(si2.x + si2.y);
        const float sg = qsum(sg2.x + sg2.y);
        const float so = qsum(so2.x + so2.y);

        float val = (e == 0) ? sf : (e == 1) ? si : (e == 2) ? sg : so;
        val += xv;
        const float tz  = __expf(A * val);
        const float act = fmaf(-A, __builtin_amdgcn_rcpf(tz + 1.f), 1.f);

        const float iv = dppmov<0x39>(act);
        const float gv = dppmov<0x4E>(act);
        const float ov = dppmov<0x93>(act);
        c  = fmaf(act, c, iv * gv);
        hh = tanh_fast(c) * ov;

        if (e == 0) {
            hP[(t + 1) & 1][p >> 5][p & 31] = hh;
            hob[(size_t)t * H_ + p] = hh;
        }
        xv = xvn;
        __syncthreads();
    }
    if (e == 0) { h1st[b * H_ + p] = hh; c1st[b * H_ + p] = c; }
}

// ---------------- 2-batch layer-0 body (r18) ----------------
__device__ __forceinline__ void l0_body2(
    const int j, const int bb,
    const int* __restrict__ x, const float* __restrict__ table0,
    const float* __restrict__ wh0,
    float* __restrict__ h0st, float* __restrict__ c0st,
    float* __restrict__ h0buf, int t0, int TC,
    float (*hPA)[4][36], float (*hPB)[4][36])
{
    const int p = j >> 2;
    const int e = j & 3;
    const int kb = 32 * e;

    const float* wmat = wh0;
    REPEAT16(DECLW)
    REPEAT16(LOADW)
    if (j < H_) {
        hPA[0][j >> 5][j & 31] = h0st[(size_t)bb * H_ + j];
        hPB[0][j >> 5][j & 31] = h0st[(size_t)(bb + 1) * H_ + j];
    }
    float cA = c0st[(size_t)bb * H_ + p];
    float cB = c0st[(size_t)(bb + 1) * H_ + p];
    float hhA = 0.f, hhB = 0.f;
    __syncthreads();

    const int* xbA = x + (size_t)bb * T_ + t0;
    const int* xbB = x + (size_t)(bb + 1) * T_ + t0;
    float* hobA = h0buf + (size_t)bb * TC * H_;
    float* hobB = h0buf + (size_t)(bb + 1) * TC * H_;
    const float A = (e == 2) ? 2.f : 1.f;
    const int toff = e * 132 + p;

    float tvA = table0[xbA[0] * TPITCH + toff];
    float tvB = table0[xbB[0] * TPITCH + toff];
    for (int t = 0; t < TC; ++t) {
        REPEAT16(PINW)
        const int idxnA = (t + 1 < TC) ? xbA[t + 1] : 0;
        const int idxnB = (t + 1 < TC) ? xbB[t + 1] : 0;

        const float4* ha4 = reinterpret_cast<const float4*>(&hPA[t & 1][e][0]);
        const float4 uA0 = ha4[0], uA1 = ha4[1], uA2 = ha4[2], uA3 = ha4[3],
                     uA4 = ha4[4], uA5 = ha4[5], uA6 = ha4[6], uA7 = ha4[7];
        v2f sfA = mkv2(0.f, 0.f), siA = sfA, sgA = sfA, soA = sfA;
        FMABODY2(uA, sfA, siA, sgA, soA)

        const float4* hb4 = reinterpret_cast<const float4*>(&hPB[t & 1][e][0]);
        const float4 uB0 = hb4[0], uB1 = hb4[1], uB2 = hb4[2], uB3 = hb4[3],
                     uB4 = hb4[4], uB5 = hb4[5], uB6 = hb4[6], uB7 = hb4[7];
        v2f sfB = mkv2(0.f, 0.f), siB = sfB, sgB = sfB, soB = sfB;
        FMABODY2(uB, sfB, siB, sgB, soB)

        const float rfA = qsum(sfA.x + sfA.y);
        const float riA = qsum(siA.x + siA.y);
        const float rgA = qsum(sgA.x + sgA.y);
        const float roA = qsum(soA.x + soA.y);
        const float rfB = qsum(sfB.x + sfB.y);
        const float riB = qsum(siB.x + siB.y);
        const float rgB = qsum(sgB.x + sgB.y);
        const float roB = qsum(soB.x + soB.y);

        float valA = (e == 0) ? rfA : (e == 1) ? riA : (e == 2) ? rgA : roA;
        float valB = (e == 0) ? rfB : (e == 1) ? riB : (e == 2) ? rgB : roB;
        valA += tvA; valB += tvB;
        const float actA = fmaf(-A, __builtin_amdgcn_rcpf(__expf(A * valA) + 1.f), 1.f);
        const float actB = fmaf(-A, __builtin_amdgcn_rcpf(__expf(A * valB) + 1.f), 1.f);

        const float ivA = dppmov<0x39>(actA);
        const float gvA = dppmov<0x4E>(actA);
        const float ovA = dppmov<0x93>(actA);
        cA  = fmaf(actA, cA, ivA * gvA);
        hhA = tanh_fast(cA) * ovA;
        const float ivB = dppmov<0x39>(actB);
        const float gvB = dppmov<0x4E>(actB);
        const float ovB = dppmov<0x93>(actB);
        cB  = fmaf(actB, cB, ivB * gvB);
        hhB = tanh_fast(cB) * ovB;

        if (e == 0) {
            hPA[(t + 1) & 1][p >> 5][p & 31] = hhA;
            hPB[(t + 1) & 1][p >> 5][p & 31] = hhB;
            hobA[(size_t)t * H_ + p] = hhA;
            hobB[(size_t)t * H_ + p] = hhB;
        }
        tvA = table0[idxnA * TPITCH + toff];
        tvB = table0[idxnB * TPITCH + toff];
        __syncthreads();
    }
    if (e == 0) {
        h0st[(size_t)bb * H_ + p] = hhA;       c0st[(size_t)bb * H_ + p] = cA;
        h0st[(size_t)(bb + 1) * H_ + p] = hhB; c0st[(size_t)(bb + 1) * H_ + p] = cB;
    }
}

// ---------------- 2-batch layer-1 body (r18) ----------------
__device__ __forceinline__ void l1_body2(
    const int j, const int bb,
    const float* __restrict__ xg1, const float* __restrict__ wh1,
    float* __restrict__ h1st, float* __restrict__ c1st,
    float* __restrict__ h1buf, int TC,
    float (*hPA)[4][36], float (*hPB)[4][36])
{
    const int p = j >> 2;
    const int e = j & 3;
    const int kb = 32 * e;

    const float* wmat = wh1;
    REPEAT16(DECLW)
    REPEAT16(LOADW)
    if (j < H_) {
        hPA[0][j >> 5][j & 31] = h1st[(size_t)bb * H_ + j];
        hPB[0][j >> 5][j & 31] = h1st[(size_t)(bb + 1) * H_ + j];
    }
    float cA = c1st[(size_t)bb * H_ + p];
    float cB = c1st[(size_t)(bb + 1) * H_ + p];
    float hhA = 0.f, hhB = 0.f;
    __syncthreads();

    const float* xgA = xg1 + (size_t)bb * TC * G4;
    const float* xgB = xg1 + (size_t)(bb + 1) * TC * G4;
    float* hobA = h1buf + (size_t)bb * TC * H_;
    float* hobB = h1buf + (size_t)(bb + 1) * TC * H_;
    const float A = (e == 2) ? 2.f : 1.f;
    const int xcol = e * H_ + p;

    float xvA = xgA[xcol];
    float xvB = xgB[xcol];
    for (int t = 0; t < TC; ++t) {
        REPEAT16(PINW)
        const float xvnA = (t + 1 < TC) ? xgA[(size_t)(t + 1) * G4 + xcol] : 0.f;
        const float xvnB = (t + 1 < TC) ? xgB[(size_t)(t + 1) * G4 + xcol] : 0.f;

        const float4* ha4 = reinterpret_cast<const float4*>(&hPA[t & 1][e][0]);
        const float4 uA0 = ha4[0], uA1 = ha4[1], uA2 = ha4[2], uA3 = ha4[3],
                     uA4 = ha4[4], uA5 = ha4[5], uA6 = ha4[6], uA7 = ha4[7];
        v2f sfA = mkv2(0.f, 0.f), siA = sfA, sgA = sfA, soA = sfA;
        FMABODY2(uA, sfA, siA, sgA, soA)

        const float4* hb4 = reinterpret_cast<const float4*>(&hPB[t & 1][e][0]);
        const float4 uB0 = hb4[0], uB1 = hb4[1], uB2 = hb4[2], uB3 = hb4[3],
                     uB4 = hb4[4], uB5 = hb4[5], uB6 = hb4[6], uB7 = hb4[7];
        v2f sfB = mkv2(0.f, 0.f), siB = sfB, sgB = sfB, soB = sfB;
        FMABODY2(uB, sfB, siB, sgB, soB)

        const float rfA = qsum(sfA.x + sfA.y);
        const float riA = qsum(siA.x + siA.y);
        const float rgA = qsum(sgA.x + sgA.y);
        const float roA = qsum(soA.x + soA.y);
        const float rfB = qsum(sfB.x + sfB.y);
        const float riB = qsum(siB.x + siB.y);
        const float rgB = qsum(sgB.x + sgB.y);
        const float roB = qsum(soB.x + soB.y);

        float valA = (e == 0) ? rfA : (e == 1) ? riA : (e == 2) ? rgA : roA;
        float valB = (e == 0) ? rfB : (e == 1) ? riB : (e == 2) ? rgB : roB;
        valA += xvA; valB += xvB;
        const float actA = fmaf(-A, __builtin_amdgcn_rcpf(__expf(A * valA) + 1.f), 1.f);
        const float actB = fmaf(-A, __builtin_amdgcn_rcpf(__expf(A * valB) + 1.f), 1.f);

        const float ivA = dppmov<0x39>(actA);
        const float gvA = dppmov<0x4E>(actA);
        const float ovA = dppmov<0x93>(actA);
        cA  = fmaf(actA, cA, ivA * gvA);
        hhA = tanh_fast(cA) * ovA;
        const float ivB = dppmov<0x39>(actB);
        const float gvB = dppmov<0x4E>(actB);
        const float ovB = dppmov<0x93>(actB);
        cB  = fmaf(actB, cB, ivB * gvB);
        hhB = tanh_fast(cB) * ovB;

        if (e == 0) {
            hPA[(t + 1) & 1][p >> 5][p & 31] = hhA;
            hPB[(t + 1) & 1][p >> 5][p & 31] = hhB;
            hobA[(size_t)t * H_ + p] = hhA;
            hobB[(size_t)t * H_ + p] = hhB;
        }
        xvA = xvnA; xvB = xvnB;
        __syncthreads();
    }
    if (e == 0) {
        h1st[(size_t)bb * H_ + p] = hhA;       c1st[(size_t)bb * H_ + p] = cA;
        h1st[(size_t)(bb + 1) * H_ + p] = hhB; c1st[(size_t)(bb + 1) * H_ + p] = cB;
    }
}

// ---------------- fused: 128 blocks l1(c) + 128 blocks l0(c+1) ----------------
__global__ __launch_bounds__(512, 2)
void lstm_fused2(const int* __restrict__ x, const float* __restrict__ table0,
                 const float* __restrict__ wh0,
                 const float* __restrict__ xg1, const float* __restrict__ wh1,
                 float* __restrict__ h0st, float* __restrict__ c0st,
                 float* __restrict__ h0buf,
                 float* __restrict__ h1st, float* __restrict__ c1st,
                 float* __restrict__ h1buf,
                 int t0_l0, int TC)
{
    __shared__ __align__(16) float hPA[2][4][36];
    __shared__ __align__(16) float hPB[2][4][36];
    const int bid = blockIdx.x;
    if (bid < B_ / 2) {
        l1_body2(threadIdx.x, 2 * bid, xg1, wh1, h1st, c1st, h1buf, TC,
                 hPA, hPB);
    } else {
        l0_body2(threadIdx.x, 2 * (bid - B_ / 2), x, table0, wh0,
                 h0st, c0st, h0buf, t0_l0, TC, hPA, hPB);
    }
}

// ---------------- P2: xg1 = h0 @ wx1 + b1 ----------------
__global__ __launch_bounds__(G4, 2)
void gemm_xg1(const float* __restrict__ h0buf,
              const float* __restrict__ wx1,
              const float* __restrict__ b1,
              float* __restrict__ xg1)
{
    const int j  = threadIdx.x;
    const size_t m0 = (size_t)blockIdx.x * 64;
    const int c  = j & 127;
    const int rg = j >> 7;

    __shared__ __align__(16) float aT[64 * 132];

#pragma unroll
    for (int i = 0; i < 4; ++i) {
        const int e  = i * G4 + j;
        const int r  = e >> 5;
        const int k4 = e & 31;
        const float4 v = *reinterpret_cast<const float4*>(&h0buf[(m0 + r) * H_ + k4 * 4]);
        *reinterpret_cast<float4*>(&aT[r * 132 + k4 * 4]) = v;
    }
    __syncthreads();

    float acc[4][16];
#pragma unroll
    for (int cc = 0; cc < 4; ++cc)
#pragma unroll
        for (int rr = 0; rr < 16; ++rr) acc[cc][rr] = 0.f;

    for (int k4 = 0; k4 < 32; ++k4) {
        float bv[4][4];
#pragma unroll
        for (int kk = 0; kk < 4; ++kk)
#pragma unroll
            for (int cc = 0; cc < 4; ++cc)
                bv[kk][cc] = wx1[(size_t)(k4 * 4 + kk) * G4 + cc * 128 + c];
#pragma unroll
        for (int rr = 0; rr < 16; ++rr) {
            const float4 av = *reinterpret_cast<const float4*>(&aT[(rg * 16 + rr) * 132 + k4 * 4]);
#pragma unroll
            for (int cc = 0; cc < 4; ++cc) {
                acc[cc][rr] = fmaf(av.x, bv[0][cc], acc[cc][rr]);
                acc[cc][rr] = fmaf(av.y, bv[1][cc], acc[cc][rr]);
                acc[cc][rr] = fmaf(av.z, bv[2][cc], acc[cc][rr]);
                acc[cc][rr] = fmaf(av.w, bv[3][cc], acc[cc][rr]);
            }
        }
    }

    float b1v[4];
#pragma unroll
    for (int cc = 0; cc < 4; ++cc) b1v[cc] = b1[cc * 128 + c];
#pragma unroll
    for (int rr = 0; rr < 16; ++rr) {
        const size_t row = m0 + rg * 16 + rr;
#pragma unroll
        for (int cc = 0; cc < 4; ++cc)
            xg1[row * G4 + cc * 128 + c] = acc[cc][rr] + b1v[cc];
    }
}

// ---------------- P4: y = h1 @ why + by ----------------
__global__ __launch_bounds__(256)
void proj_y(const float* __restrict__ h1buf,
            const float* __restrict__ why,
            const float* __restrict__ by,
            float* __restrict__ out,
            int t0, int TC)
{
    const int tid = threadIdx.x;
    const int b   = blockIdx.x;

    __shared__ __align__(16) float whyS[V_][H_];
    __shared__ float byS[V_];
    __shared__ float yS[256][29];

    for (int e = tid; e < V_ * H_; e += 256) {
        const int v = e / H_, k = e - v * H_;
        whyS[v][k] = why[k * V_ + v];
    }
    if (tid < V_) byS[tid] = by[tid];
    __syncthreads();

    const float* hb  = h1buf + (size_t)b * TC * H_;
    float* outb      = out + ((size_t)b * T_ + t0) * V_;

    for (int tt0 = 0; tt0 < TC; tt0 += 256) {
        const int tt = tt0 + tid;
        if (tt < TC) {
            float acc[V_];
#pragma unroll
            for (int v = 0; v < V_; ++v) acc[v] = byS[v];
            const float4* hr = reinterpret_cast<const float4*>(hb + (size_t)tt * H_);
#pragma unroll 4
            for (int k4 = 0; k4 < 32; ++k4) {
                const float4 hv = hr[k4];
#pragma unroll
                for (int v = 0; v < V_; ++v) {
                    const float4 wv = *reinterpret_cast<const float4*>(&whyS[v][k4 * 4]);
                    acc[v] = fmaf(hv.x, wv.x,
                             fmaf(hv.y, wv.y,
                             fmaf(hv.z, wv.z,
                             fmaf(hv.w, wv.w, acc[v]))));
                }
            }
#pragma unroll
            for (int v = 0; v < V_; ++v) yS[tid][v] = acc[v];
        }
        __syncthreads();
        const int nrow = (TC - tt0 < 256) ? (TC - tt0) : 256;
        const int n = nrow * V_;
        float* od = outb + (size_t)tt0 * V_;
        for (int i = tid; i < n; i += 256) {
            const int r = i / V_, v = i - r * V_;
            od[i] = yS[r][v];
        }
        __syncthreads();
    }
}

// ---------------- fallback: streaming kernel (uses [v][4][132] table) ----------------
__global__ __launch_bounds__(G4, 1)
void lstm_persist(const int* __restrict__ x,
                  const float* __restrict__ table0,
                  const float* __restrict__ wh0,
                  const float* __restrict__ wx1,
                  const float* __restrict__ wh1,
                  const float* __restrict__ b1,
                  const float* __restrict__ why,
                  const float* __restrict__ by,
                  float* __restrict__ out)
{
    const int j  = threadIdx.x;
    const int bb = blockIdx.x * 2;

    __shared__ float h0s[2][H_], c0s[2][H_], h1s[2][H_], c1s[2][H_];
    __shared__ float hcat[2][2 * H_];
    __shared__ float g0s[2][G4], g1s[2][G4];
    __shared__ float whyS[H_ * V_];
    __shared__ float b1S[G4];
    __shared__ float byS[V_];
    __shared__ float pb[2][V_][8];

    for (int i = j; i < H_ * V_; i += G4) whyS[i] = why[i];
    b1S[j] = b1[j];
    if (j < V_) byS[j] = by[j];
    if (j < H_) {
        h0s[0][j] = 0.f; h0s[1][j] = 0.f; c0s[0][j] = 0.f; c0s[1][j] = 0.f;
        h1s[0][j] = 0.f; h1s[1][j] = 0.f; c1s[0][j] = 0.f; c1s[1][j] = 0.f;
    }
    __syncthreads();

    const int* xA = x + (size_t)(bb + 0) * T_;
    const int* xB = x + (size_t)(bb + 1) * T_;
    float* outA = out + (size_t)(bb + 0) * T_ * V_;
    float* outB = out + (size_t)(bb + 1) * T_ * V_;

    const int tix = (j >> 7) * 132 + (j & (H_ - 1));

    for (int t = 0; t < T_; ++t) {
        const int ia = xA[t];
        const int ib = xB[t];
        float aA = table0[ia * TPITCH + tix];
        float aB = table0[ib * TPITCH + tix];
#pragma unroll 8
        for (int k = 0; k < H_; ++k) {
            const float w = wh0[k * G4 + j];
            aA += h0s[0][k] * w;
            aB += h0s[1][k] * w;
        }
        g0s[0][j] = aA; g0s[1][j] = aB;
        __syncthreads();

        if (j < 2 * H_) {
            const int gi = j >> 7, r = j & (H_ - 1);
            const float f  = 1.f / (1.f + expf(-g0s[gi][r]));
            const float i_ = 1.f / (1.f + expf(-g0s[gi][H_ + r]));
            const float g  = tanhf(g0s[gi][2 * H_ + r]);
            const float o  = 1.f / (1.f + expf(-g0s[gi][3 * H_ + r]));
            const float c  = f * c0s[gi][r] + i_ * g;
            c0s[gi][r] = c;
            const float h = tanhf(c) * o;
            h0s[gi][r] = h;
            hcat[gi][r] = h;
            hcat[gi][H_ + r] = h1s[gi][r];
        }
        __syncthreads();

        float bA = b1S[j];
        float bB = bA;
#pragma unroll 8
        for (int k = 0; k < H_; ++k) {
            const float w = wx1[k * G4 + j];
            bA += hcat[0][k] * w;
            bB += hcat[1][k] * w;
        }
#pragma unroll 8
        for (int k = 0; k < H_; ++k) {
            const float w = wh1[k * G4 + j];
            bA += hcat[0][H_ + k] * w;
            bB += hcat[1][H_ + k] * w;
        }
        g1s[0][j] = bA; g1s[1][j] = bB;
        __syncthreads();

        if (j < 2 * H_) {
            const int gi = j >> 7, r = j & (H_ - 1);
            const float f  = 1.f / (1.f + expf(-g1s[gi][r]));
            const float i_ = 1.f / (1.f + expf(-g1s[gi][H_ + r]));
            const float g  = tanhf(g1s[gi][2 * H_ + r]);
            const float o  = 1.f / (1.f + expf(-g1s[gi][3 * H_ + r]));
            const float c  = f * c1s[gi][r] + i_ * g;
            c1s[gi][r] = c;
            h1s[gi][r] = tanhf(c) * o;
        }
        __syncthreads();

        if (j < 2 * V_ * 8) {
            int qq = j;
            const int gi = (qq >= V_ * 8) ? 1 : 0;
            qq -= gi * V_ * 8;
            const int v = qq >> 3, kk = qq & 7;
            float pv = 0.f;
#pragma unroll
            for (int k = kk * 16; k < kk * 16 + 16; ++k)
                pv += h1s[gi][k] * whyS[k * V_ + v];
            pb[gi][v][kk] = pv;
        }
        __syncthreads();

        if (j < 2 * V_) {
            const int gi = (j >= V_) ? 1 : 0;
            const int v  = j - gi * V_;
            float sA = byS[v];
#pragma unroll
            for (int qq = 0; qq < 8; ++qq) sA += pb[gi][v][qq];
            (gi ? outB : outA)[t * V_ + v] = sA;
        }
        __syncthreads();
    }
}

// ---------------- host ----------------
extern "C" void kernel_launch(void* const* d_in, const int* in_sizes, int n_in,
                              void* d_out, int out_size, void* d_ws, size_t ws_size,
                              hipStream_t stream)
{
    const int*   x   = (const int*)  d_in[0];
    const float* emb = (const float*)d_in[1];
    const float* wx0 = (const float*)d_in[2];
    const float* wh0 = (const float*)d_in[3];
    const float* b0  = (const float*)d_in[4];
    const float* wx1 = (const float*)d_in[5];
    const float* wh1 = (const float*)d_in[6];
    const float* b1  = (const float*)d_in[7];
    const float* why = (const float*)d_in[8];
    const float* by  = (const float*)d_in[9];
    float* out = (float*)d_out;
    float* wsf = (float*)d_ws;

    const size_t tabF   = (size_t)V_ * TPITCH;   // 14256 floats
    const size_t stateF = (size_t)4 * B_ * H_;   // 131072 floats

    int TC = 0;
    for (int tc = 256; tc >= 32; tc >>= 1) {
        const size_t need = (tabF + stateF + (size_t)B_ * tc * (H_ + G4 + H_)) * 4;
        if (need <= ws_size) { TC = tc; break; }
    }

    float* table0 = wsf;
    build_table0<<<dim3(V_), dim3(G4), 0, stream>>>(emb, wx0, b0, table0);

    if (TC == 0) {
        lstm_persist<<<dim3(B_ / 2), dim3(G4), 0, stream>>>(
            x, table0, wh0, wx1, wh1, b1, why, by, out);
        return;
    }

    float* h0st   = wsf + tabF;
    float* c0st   = h0st + (size_t)B_ * H_;
    float* h1st   = c0st + (size_t)B_ * H_;
    float* c1st   = h1st + (size_t)B_ * H_;
    float* h0buf  = c1st + (size_t)B_ * H_;
    float* xg1buf = h0buf + (size_t)B_ * TC * H_;
    float* h1buf  = xg1buf + (size_t)B_ * TC * G4;

    (void)hipMemsetAsync(h0st, 0, stateF * sizeof(float), stream);

    const int NC = T_ / TC;

    // fill: full-width single-batch l0 on chunk 0 (256 blocks) + its gemm
    lstm_l0_1b<<<dim3(B_), dim3(512), 0, stream>>>(
        x, table0, wh0, h0st, c0st, h0buf, 0, TC);
    gemm_xg1<<<dim3(4 * TC), dim3(G4), 0, stream>>>(h0buf, wx1, b1, xg1buf);

    // pipelined middle: fused{l1(c) || l0(c+1)}; gemm(c+1); proj(c)
    for (int c = 0; c < NC - 1; ++c) {
        lstm_fused2<<<dim3(B_), dim3(512), 0, stream>>>(
            x, table0, wh0, xg1buf, wh1,
            h0st, c0st, h0buf, h1st, c1st, h1buf,
            (c + 1) * TC, TC);
        gemm_xg1<<<dim3(4 * TC), dim3(G4), 0, stream>>>(h0buf, wx1, b1, xg1buf);
        proj_y<<<dim3(B_), dim3(256), 0, stream>>>(
            h1buf, why, by, out, c * TC, TC);
    }

    // drain: full-width single-batch l1 on last chunk (256 blocks) + proj
    lstm_l1_1b<<<dim3(B_), dim3(512), 0, stream>>>(
        xg1buf, wh1, h1st, c1st, h1buf, TC);
    proj_y<<<dim3(B_), dim3(256), 0, stream>>>(
        h1buf, why, by, out, (NC - 1) * TC, TC);
}

// Round 21
// 1764.703 us; speedup vs baseline: 1.1485x; 1.0245x over previous
//
#include <hip/hip_runtime.h>

// MultiLayerLSTM: B=256, T=1024, V=27, E=64, H=128 (4H=512)
// Round 21: r20 merged gemm+proj dispatch with the LDS overflow fixed.
//   r20 sized the shared scratch for gemm (64*132=8448 floats) but proj
//   needs V*H+32+256*29=10912 -> yS ran 2464 floats past the buffer,
//   corrupting LDS (absmax 1.4e-3). Fix: smem[10944] in gemm_proj and
//   proj_y (43.8KB; 2 blocks/CU = 87.5KB < 160KB, occupancy unchanged).
// Schedule: P0 table; l0_1b(0); gemm(0);
//   {fused2(l1(c)||l0(c+1)); merged{gemm(c+1)||proj(c)}} x (NC-1);
//   l1_1b(NC-1); proj(NC-1).

#define B_  256
#define T_  1024
#define V_  27
#define E_  64
#define H_  128
#define G4  512     // 4*H
#define TPITCH 528  // 4*132 padded table pitch per vocab entry
#define SMEMF 10944 // max(gemm 8448, proj 10912) + pad

typedef float v2f __attribute__((ext_vector_type(2)));

__device__ __forceinline__ v2f mkv2(float a, float b) { v2f r; r.x = a; r.y = b; return r; }

template <int CTRL>
__device__ __forceinline__ float dppmov(float v) {
    return __int_as_float(__builtin_amdgcn_update_dpp(
               0, __float_as_int(v), CTRL, 0xF, 0xF, true));
}
__device__ __forceinline__ float qsum(float v) {
    v += dppmov<0xB1>(v);   // quad_perm [1,0,3,2]
    v += dppmov<0x4E>(v);   // quad_perm [2,3,0,1]
    return v;
}
__device__ __forceinline__ float tanh_fast(float y) {
    const float t = __expf(2.f * y);             // inf-safe: tanh(+big)=1
    return fmaf(-2.f, __builtin_amdgcn_rcpf(t + 1.f), 1.f);
}

#define REPEAT16(M) M(0) M(1) M(2) M(3) M(4) M(5) M(6) M(7) \
                    M(8) M(9) M(10) M(11) M(12) M(13) M(14) M(15)

#define DECLW(K) v2f wf##K, wi##K, wg##K, wo##K;
#define LOADW(K) { const float* r0 = wmat + (size_t)(kb + 2*(K)) * G4; \
                   wf##K = mkv2(r0[p],          r0[G4 + p]); \
                   wi##K = mkv2(r0[H_ + p],     r0[G4 + H_ + p]); \
                   wg##K = mkv2(r0[2*H_ + p],   r0[G4 + 2*H_ + p]); \
                   wo##K = mkv2(r0[3*H_ + p],   r0[G4 + 3*H_ + p]); }
#define PINW(K) asm("" : "+v"(wf##K), "+v"(wi##K), "+v"(wg##K), "+v"(wo##K));

#define FMAP(K, HA, HB) { const v2f h2 = mkv2(HA, HB); \
    sf2 = __builtin_elementwise_fma(h2, wf##K, sf2); \
    si2 = __builtin_elementwise_fma(h2, wi##K, si2); \
    sg2 = __builtin_elementwise_fma(h2, wg##K, sg2); \
    so2 = __builtin_elementwise_fma(h2, wo##K, so2); }
#define FMABODY \
    v2f sf2 = mkv2(0.f, 0.f), si2 = sf2, sg2 = sf2, so2 = sf2; \
    FMAP(0,  v0.x, v0.y) FMAP(1,  v0.z, v0.w) \
    FMAP(2,  v1.x, v1.y) FMAP(3,  v1.z, v1.w) \
    FMAP(4,  v2.x, v2.y) FMAP(5,  v2.z, v2.w) \
    FMAP(6,  v3.x, v3.y) FMAP(7,  v3.z, v3.w) \
    FMAP(8,  v4.x, v4.y) FMAP(9,  v4.z, v4.w) \
    FMAP(10, v5.x, v5.y) FMAP(11, v5.z, v5.w) \
    FMAP(12, v6.x, v6.y) FMAP(13, v6.z, v6.w) \
    FMAP(14, v7.x, v7.y) FMAP(15, v7.z, v7.w)

#define FMAP2(K, HA, HB, SF, SI, SG, SO) { const v2f h2 = mkv2(HA, HB); \
    SF = __builtin_elementwise_fma(h2, wf##K, SF); \
    SI = __builtin_elementwise_fma(h2, wi##K, SI); \
    SG = __builtin_elementwise_fma(h2, wg##K, SG); \
    SO = __builtin_elementwise_fma(h2, wo##K, SO); }
#define FMABODY2(U, SF, SI, SG, SO) \
    FMAP2(0,  (U##0).x, (U##0).y, SF, SI, SG, SO) FMAP2(1,  (U##0).z, (U##0).w, SF, SI, SG, SO) \
    FMAP2(2,  (U##1).x, (U##1).y, SF, SI, SG, SO) FMAP2(3,  (U##1).z, (U##1).w, SF, SI, SG, SO) \
    FMAP2(4,  (U##2).x, (U##2).y, SF, SI, SG, SO) FMAP2(5,  (U##2).z, (U##2).w, SF, SI, SG, SO) \
    FMAP2(6,  (U##3).x, (U##3).y, SF, SI, SG, SO) FMAP2(7,  (U##3).z, (U##3).w, SF, SI, SG, SO) \
    FMAP2(8,  (U##4).x, (U##4).y, SF, SI, SG, SO) FMAP2(9,  (U##4).z, (U##4).w, SF, SI, SG, SO) \
    FMAP2(10, (U##5).x, (U##5).y, SF, SI, SG, SO) FMAP2(11, (U##5).z, (U##5).w, SF, SI, SG, SO) \
    FMAP2(12, (U##6).x, (U##6).y, SF, SI, SG, SO) FMAP2(13, (U##6).z, (U##6).w, SF, SI, SG, SO) \
    FMAP2(14, (U##7).x, (U##7).y, SF, SI, SG, SO) FMAP2(15, (U##7).z, (U##7).w, SF, SI, SG, SO)

// ---------------- P0: token table, layout [v][4][132] ----------------
__global__ __launch_bounds__(G4)
void build_table0(const float* __restrict__ emb,
                  const float* __restrict__ wx0,
                  const float* __restrict__ b0,
                  float* __restrict__ table0)
{
    const int v = blockIdx.x;        // 0..26
    const int j = threadIdx.x;       // col 0..511
    __shared__ float e[E_];
    if (j < E_) e[j] = emb[v * E_ + j];
    __syncthreads();
    float s = b0[j];
#pragma unroll 8
    for (int k = 0; k < E_; ++k) s = fmaf(e[k], wx0[k * G4 + j], s);
    const int r = j & (H_ - 1), gate = j >> 7;
    table0[v * TPITCH + gate * 132 + r] = s;
}

// ---------------- single-batch l0 (256 blocks): pipeline fill ----------------
__global__ __launch_bounds__(512, 2)
void lstm_l0_1b(const int* __restrict__ x,
                const float* __restrict__ table0,
                const float* __restrict__ wh0,
                float* __restrict__ h0st, float* __restrict__ c0st,
                float* __restrict__ h0buf,
                int t0, int TC)
{
    const int j = threadIdx.x;        // 0..511
    const int p = j >> 2;             // row 0..127
    const int e = j & 3;              // k-quarter
    const int b = blockIdx.x;
    const int kb = 32 * e;

    __shared__ __align__(16) float hP[2][4][36];

    const float* wmat = wh0;
    REPEAT16(DECLW)
    REPEAT16(LOADW)
    if (j < H_) hP[0][j >> 5][j & 31] = h0st[b * H_ + j];
    float c = c0st[b * H_ + p];
    float hh = 0.f;
    __syncthreads();

    const int* xb = x + (size_t)b * T_ + t0;
    float* hob = h0buf + (size_t)b * TC * H_;
    const float A = (e == 2) ? 2.f : 1.f;
    const int toff = e * 132 + p;

    float tv = table0[xb[0] * TPITCH + toff];
    for (int t = 0; t < TC; ++t) {
        REPEAT16(PINW)
        const int idxn = (t + 1 < TC) ? xb[t + 1] : 0;

        const float4* hb4 = reinterpret_cast<const float4*>(&hP[t & 1][e][0]);
        const float4 v0 = hb4[0], v1 = hb4[1], v2 = hb4[2], v3 = hb4[3],
                     v4 = hb4[4], v5 = hb4[5], v6 = hb4[6], v7 = hb4[7];
        FMABODY
        const float sf = qsum(sf2.x + sf2.y);
        const float si = qsum(si2.x + si2.y);
        const float sg = qsum(sg2.x + sg2.y);
        const float so = qsum(so2.x + so2.y);

        float val = (e == 0) ? sf : (e == 1) ? si : (e == 2) ? sg : so;
        val += tv;
        const float tz  = __expf(A * val);
        const float act = fmaf(-A, __builtin_amdgcn_rcpf(tz + 1.f), 1.f);

        const float iv = dppmov<0x39>(act);
        const float gv = dppmov<0x4E>(act);
        const float ov = dppmov<0x93>(act);
        c  = fmaf(act, c, iv * gv);
        hh = tanh_fast(c) * ov;

        if (e == 0) {
            hP[(t + 1) & 1][p >> 5][p & 31] = hh;
            hob[(size_t)t * H_ + p] = hh;
        }
        tv = table0[idxn * TPITCH + toff];
        __syncthreads();
    }
    if (e == 0) { h0st[b * H_ + p] = hh; c0st[b * H_ + p] = c; }
}

// ---------------- single-batch l1 (256 blocks): pipeline drain ----------------
__global__ __launch_bounds__(512, 2)
void lstm_l1_1b(const float* __restrict__ xg1,
                const float* __restrict__ wh1,
                float* __restrict__ h1st, float* __restrict__ c1st,
                float* __restrict__ h1buf,
                int TC)
{
    const int j = threadIdx.x;
    const int p = j >> 2;
    const int e = j & 3;
    const int b = blockIdx.x;
    const int kb = 32 * e;

    __shared__ __align__(16) float hP[2][4][36];

    const float* wmat = wh1;
    REPEAT16(DECLW)
    REPEAT16(LOADW)
    if (j < H_) hP[0][j >> 5][j & 31] = h1st[b * H_ + j];
    float c = c1st[b * H_ + p];
    float hh = 0.f;
    __syncthreads();

    const float* xgb = xg1 + (size_t)b * TC * G4;
    float* hob = h1buf + (size_t)b * TC * H_;
    const float A = (e == 2) ? 2.f : 1.f;
    const int xcol = e * H_ + p;

    float xv = xgb[xcol];
    for (int t = 0; t < TC; ++t) {
        REPEAT16(PINW)
        const float xvn = (t + 1 < TC) ? xgb[(size_t)(t + 1) * G4 + xcol] : 0.f;

        const float4* hb4 = reinterpret_cast<const float4*>(&hP[t & 1][e][0]);
        const float4 v0 = hb4[0], v1 = hb4[1], v2 = hb4[2], v3 = hb4[3],
                     v4 = hb4[4], v5 = hb4[5], v6 = hb4[6], v7 = hb4[7];
        FMABODY
        const float sf = qsum(sf2.x + sf2.y);
        const float si = qsum(si2.x + si2.y);
        const float sg = qsum(sg2.x + sg2.y);
        const float so = qsum(so2.x + so2.y);

        float val = (e == 0) ? sf : (e == 1) ? si : (e == 2) ? sg : so;
        val += xv;
        const float tz  = __expf(A * val);
        const float act = fmaf(-A, __builtin_amdgcn_rcpf(tz + 1.f), 1.f);

        const float iv = dppmov<0x39>(act);
        const float gv = dppmov<0x4E>(act);
        const float ov = dppmov<0x93>(act);
        c  = fmaf(act, c, iv * gv);
        hh = tanh_fast(c) * ov;

        if (e == 0) {
            hP[(t + 1) & 1][p >> 5][p & 31] = hh;
            hob[(size_t)t * H_ + p] = hh;
        }
        xv = xvn;
        __syncthreads();
    }
    if (e == 0) { h1st[b * H_ + p] = hh; c1st[b * H_ + p] = c; }
}

// ---------------- 2-batch layer-0 body ----------------
__device__ __forceinline__ void l0_body2(
    const int j, const int bb,
    const int* __restrict__ x, const float* __restrict__ table0,
    const float* __restrict__ wh0,
    float* __restrict__ h0st, float* __restrict__ c0st,
    float* __restrict__ h0buf, int t0, int TC,
    float (*hPA)[4][36], float (*hPB)[4][36])
{
    const int p = j >> 2;
    const int e = j & 3;
    const int kb = 32 * e;

    const float* wmat = wh0;
    REPEAT16(DECLW)
    REPEAT16(LOADW)
    if (j < H_) {
        hPA[0][j >> 5][j & 31] = h0st[(size_t)bb * H_ + j];
        hPB[0][j >> 5][j & 31] = h0st[(size_t)(bb + 1) * H_ + j];
    }
    float cA = c0st[(size_t)bb * H_ + p];
    float cB = c0st[(size_t)(bb + 1) * H_ + p];
    float hhA = 0.f, hhB = 0.f;
    __syncthreads();

    const int* xbA = x + (size_t)bb * T_ + t0;
    const int* xbB = x + (size_t)(bb + 1) * T_ + t0;
    float* hobA = h0buf + (size_t)bb * TC * H_;
    float* hobB = h0buf + (size_t)(bb + 1) * TC * H_;
    const float A = (e == 2) ? 2.f : 1.f;
    const int toff = e * 132 + p;

    float tvA = table0[xbA[0] * TPITCH + toff];
    float tvB = table0[xbB[0] * TPITCH + toff];
    for (int t = 0; t < TC; ++t) {
        REPEAT16(PINW)
        const int idxnA = (t + 1 < TC) ? xbA[t + 1] : 0;
        const int idxnB = (t + 1 < TC) ? xbB[t + 1] : 0;

        const float4* ha4 = reinterpret_cast<const float4*>(&hPA[t & 1][e][0]);
        const float4 uA0 = ha4[0], uA1 = ha4[1], uA2 = ha4[2], uA3 = ha4[3],
                     uA4 = ha4[4], uA5 = ha4[5], uA6 = ha4[6], uA7 = ha4[7];
        v2f sfA = mkv2(0.f, 0.f), siA = sfA, sgA = sfA, soA = sfA;
        FMABODY2(uA, sfA, siA, sgA, soA)

        const float4* hb4 = reinterpret_cast<const float4*>(&hPB[t & 1][e][0]);
        const float4 uB0 = hb4[0], uB1 = hb4[1], uB2 = hb4[2], uB3 = hb4[3],
                     uB4 = hb4[4], uB5 = hb4[5], uB6 = hb4[6], uB7 = hb4[7];
        v2f sfB = mkv2(0.f, 0.f), siB = sfB, sgB = sfB, soB = sfB;
        FMABODY2(uB, sfB, siB, sgB, soB)

        const float rfA = qsum(sfA.x + sfA.y);
        const float riA = qsum(siA.x + siA.y);
        const float rgA = qsum(sgA.x + sgA.y);
        const float roA = qsum(soA.x + soA.y);
        const float rfB = qsum(sfB.x + sfB.y);
        const float riB = qsum(siB.x + siB.y);
        const float rgB = qsum(sgB.x + sgB.y);
        const float roB = qsum(soB.x + soB.y);

        float valA = (e == 0) ? rfA : (e == 1) ? riA : (e == 2) ? rgA : roA;
        float valB = (e == 0) ? rfB : (e == 1) ? riB : (e == 2) ? rgB : roB;
        valA += tvA; valB += tvB;
        const float actA = fmaf(-A, __builtin_amdgcn_rcpf(__expf(A * valA) + 1.f), 1.f);
        const float actB = fmaf(-A, __builtin_amdgcn_rcpf(__expf(A * valB) + 1.f), 1.f);

        const float ivA = dppmov<0x39>(actA);
        const float gvA = dppmov<0x4E>(actA);
        const float ovA = dppmov<0x93>(actA);
        cA  = fmaf(actA, cA, ivA * gvA);
        hhA = tanh_fast(cA) * ovA;
        const float ivB = dppmov<0x39>(actB);
        const float gvB = dppmov<0x4E>(actB);
        const float ovB = dppmov<0x93>(actB);
        cB  = fmaf(actB, cB, ivB * gvB);
        hhB = tanh_fast(cB) * ovB;

        if (e == 0) {
            hPA[(t + 1) & 1][p >> 5][p & 31] = hhA;
            hPB[(t + 1) & 1][p >> 5][p & 31] = hhB;
            hobA[(size_t)t * H_ + p] = hhA;
            hobB[(size_t)t * H_ + p] = hhB;
        }
        tvA = table0[idxnA * TPITCH + toff];
        tvB = table0[idxnB * TPITCH + toff];
        __syncthreads();
    }
    if (e == 0) {
        h0st[(size_t)bb * H_ + p] = hhA;       c0st[(size_t)bb * H_ + p] = cA;
        h0st[(size_t)(bb + 1) * H_ + p] = hhB; c0st[(size_t)(bb + 1) * H_ + p] = cB;
    }
}

// ---------------- 2-batch layer-1 body ----------------
__device__ __forceinline__ void l1_body2(
    const int j, const int bb,
    const float* __restrict__ xg1, const float* __restrict__ wh1,
    float* __restrict__ h1st, float* __restrict__ c1st,
    float* __restrict__ h1buf, int TC,
    float (*hPA)[4][36], float (*hPB)[4][36])
{
    const int p = j >> 2;
    const int e = j & 3;
    const int kb = 32 * e;

    const float* wmat = wh1;
    REPEAT16(DECLW)
    REPEAT16(LOADW)
    if (j < H_) {
        hPA[0][j >> 5][j & 31] = h1st[(size_t)bb * H_ + j];
        hPB[0][j >> 5][j & 31] = h1st[(size_t)(bb + 1) * H_ + j];
    }
    float cA = c1st[(size_t)bb * H_ + p];
    float cB = c1st[(size_t)(bb + 1) * H_ + p];
    float hhA = 0.f, hhB = 0.f;
    __syncthreads();

    const float* xgA = xg1 + (size_t)bb * TC * G4;
    const float* xgB = xg1 + (size_t)(bb + 1) * TC * G4;
    float* hobA = h1buf + (size_t)bb * TC * H_;
    float* hobB = h1buf + (size_t)(bb + 1) * TC * H_;
    const float A = (e == 2) ? 2.f : 1.f;
    const int xcol = e * H_ + p;

    float xvA = xgA[xcol];
    float xvB = xgB[xcol];
    for (int t = 0; t < TC; ++t) {
        REPEAT16(PINW)
        const float xvnA = (t + 1 < TC) ? xgA[(size_t)(t + 1) * G4 + xcol] : 0.f;
        const float xvnB = (t + 1 < TC) ? xgB[(size_t)(t + 1) * G4 + xcol] : 0.f;

        const float4* ha4 = reinterpret_cast<const float4*>(&hPA[t & 1][e][0]);
        const float4 uA0 = ha4[0], uA1 = ha4[1], uA2 = ha4[2], uA3 = ha4[3],
                     uA4 = ha4[4], uA5 = ha4[5], uA6 = ha4[6], uA7 = ha4[7];
        v2f sfA = mkv2(0.f, 0.f), siA = sfA, sgA = sfA, soA = sfA;
        FMABODY2(uA, sfA, siA, sgA, soA)

        const float4* hb4 = reinterpret_cast<const float4*>(&hPB[t & 1][e][0]);
        const float4 uB0 = hb4[0], uB1 = hb4[1], uB2 = hb4[2], uB3 = hb4[3],
                     uB4 = hb4[4], uB5 = hb4[5], uB6 = hb4[6], uB7 = hb4[7];
        v2f sfB = mkv2(0.f, 0.f), siB = sfB, sgB = sfB, soB = sfB;
        FMABODY2(uB, sfB, siB, sgB, soB)

        const float rfA = qsum(sfA.x + sfA.y);
        const float riA = qsum(siA.x + siA.y);
        const float rgA = qsum(sgA.x + sgA.y);
        const float roA = qsum(soA.x + soA.y);
        const float rfB = qsum(sfB.x + sfB.y);
        const float riB = qsum(siB.x + siB.y);
        const float rgB = qsum(sgB.x + sgB.y);
        const float roB = qsum(soB.x + soB.y);

        float valA = (e == 0) ? rfA : (e == 1) ? riA : (e == 2) ? rgA : roA;
        float valB = (e == 0) ? rfB : (e == 1) ? riB : (e == 2) ? rgB : roB;
        valA += xvA; valB += xvB;
        const float actA = fmaf(-A, __builtin_amdgcn_rcpf(__expf(A * valA) + 1.f), 1.f);
        const float actB = fmaf(-A, __builtin_amdgcn_rcpf(__expf(A * valB) + 1.f), 1.f);

        const float ivA = dppmov<0x39>(actA);
        const float gvA = dppmov<0x4E>(actA);
        const float ovA = dppmov<0x93>(actA);
        cA  = fmaf(actA, cA, ivA * gvA);
        hhA = tanh_fast(cA) * ovA;
        const float ivB = dppmov<0x39>(actB);
        const float gvB = dppmov<0x4E>(actB);
        const float ovB = dppmov<0x93>(actB);
        cB  = fmaf(actB, cB, ivB * gvB);
        hhB = tanh_fast(cB) * ovB;

        if (e == 0) {
            hPA[(t + 1) & 1][p >> 5][p & 31] = hhA;
            hPB[(t + 1) & 1][p >> 5][p & 31] = hhB;
            hobA[(size_t)t * H_ + p] = hhA;
            hobB[(size_t)t * H_ + p] = hhB;
        }
        xvA = xvnA; xvB = xvnB;
        __syncthreads();
    }
    if (e == 0) {
        h1st[(size_t)bb * H_ + p] = hhA;       c1st[(size_t)bb * H_ + p] = cA;
        h1st[(size_t)(bb + 1) * H_ + p] = hhB; c1st[(size_t)(bb + 1) * H_ + p] = cB;
    }
}

// ---------------- fused: 128 blocks l1(c) + 128 blocks l0(c+1) ----------------
__global__ __launch_bounds__(512, 2)
void lstm_fused2(const int* __restrict__ x, const float* __restrict__ table0,
                 const float* __restrict__ wh0,
                 const float* __restrict__ xg1, const float* __restrict__ wh1,
                 float* __restrict__ h0st, float* __restrict__ c0st,
                 float* __restrict__ h0buf,
                 float* __restrict__ h1st, float* __restrict__ c1st,
                 float* __restrict__ h1buf,
                 int t0_l0, int TC)
{
    __shared__ __align__(16) float hPA[2][4][36];
    __shared__ __align__(16) float hPB[2][4][36];
    const int bid = blockIdx.x;
    if (bid < B_ / 2) {
        l1_body2(threadIdx.x, 2 * bid, xg1, wh1, h1st, c1st, h1buf, TC,
                 hPA, hPB);
    } else {
        l0_body2(threadIdx.x, 2 * (bid - B_ / 2), x, table0, wh0,
                 h0st, c0st, h0buf, t0_l0, TC, hPA, hPB);
    }
}

// ---------------- gemm body (shared by standalone + merged) ----------------
__device__ __forceinline__ void gemm_body(
    const int j, const int blk,
    const float* __restrict__ h0buf, const float* __restrict__ wx1,
    const float* __restrict__ b1, float* __restrict__ xg1,
    float* aT)
{
    const size_t m0 = (size_t)blk * 64;
    const int c  = j & 127;
    const int rg = j >> 7;

#pragma unroll
    for (int i = 0; i < 4; ++i) {
        const int e  = i * G4 + j;
        const int r  = e >> 5;
        const int k4 = e & 31;
        const float4 v = *reinterpret_cast<const float4*>(&h0buf[(m0 + r) * H_ + k4 * 4]);
        *reinterpret_cast<float4*>(&aT[r * 132 + k4 * 4]) = v;
    }
    __syncthreads();

    float acc[4][16];
#pragma unroll
    for (int cc = 0; cc < 4; ++cc)
#pragma unroll
        for (int rr = 0; rr < 16; ++rr) acc[cc][rr] = 0.f;

    for (int k4 = 0; k4 < 32; ++k4) {
        float bv[4][4];
#pragma unroll
        for (int kk = 0; kk < 4; ++kk)
#pragma unroll
            for (int cc = 0; cc < 4; ++cc)
                bv[kk][cc] = wx1[(size_t)(k4 * 4 + kk) * G4 + cc * 128 + c];
#pragma unroll
        for (int rr = 0; rr < 16; ++rr) {
            const float4 av = *reinterpret_cast<const float4*>(&aT[(rg * 16 + rr) * 132 + k4 * 4]);
#pragma unroll
            for (int cc = 0; cc < 4; ++cc) {
                acc[cc][rr] = fmaf(av.x, bv[0][cc], acc[cc][rr]);
                acc[cc][rr] = fmaf(av.y, bv[1][cc], acc[cc][rr]);
                acc[cc][rr] = fmaf(av.z, bv[2][cc], acc[cc][rr]);
                acc[cc][rr] = fmaf(av.w, bv[3][cc], acc[cc][rr]);
            }
        }
    }

    float b1v[4];
#pragma unroll
    for (int cc = 0; cc < 4; ++cc) b1v[cc] = b1[cc * 128 + c];
#pragma unroll
    for (int rr = 0; rr < 16; ++rr) {
        const size_t row = m0 + rg * 16 + rr;
#pragma unroll
        for (int cc = 0; cc < 4; ++cc)
            xg1[row * G4 + cc * 128 + c] = acc[cc][rr] + b1v[cc];
    }
}

// ---------------- proj body, 512-thread variant ----------------
__device__ __forceinline__ void proj_body512(
    const int tid, const int b,
    const float* __restrict__ h1buf, const float* __restrict__ why,
    const float* __restrict__ by, float* __restrict__ out,
    int t0, int TC,
    float (*whyS)[H_], float* byS, float (*yS)[29])
{
    for (int e = tid; e < V_ * H_; e += 512) {
        const int v = e / H_, k = e - v * H_;
        whyS[v][k] = why[k * V_ + v];
    }
    if (tid < V_) byS[tid] = by[tid];
    __syncthreads();

    const float* hb = h1buf + (size_t)b * TC * H_;
    float* outb     = out + ((size_t)b * T_ + t0) * V_;

    for (int tt0 = 0; tt0 < TC; tt0 += 256) {
        const int tt = tt0 + tid;
        if (tid < 256 && tt < TC) {
            float acc[V_];
#pragma unroll
            for (int v = 0; v < V_; ++v) acc[v] = byS[v];
            const float4* hr = reinterpret_cast<const float4*>(hb + (size_t)tt * H_);
#pragma unroll 4
            for (int k4 = 0; k4 < 32; ++k4) {
                const float4 hv = hr[k4];
#pragma unroll
                for (int v = 0; v < V_; ++v) {
                    const float4 wv = *reinterpret_cast<const float4*>(&whyS[v][k4 * 4]);
                    acc[v] = fmaf(hv.x, wv.x,
                             fmaf(hv.y, wv.y,
                             fmaf(hv.z, wv.z,
                             fmaf(hv.w, wv.w, acc[v]))));
                }
            }
#pragma unroll
            for (int v = 0; v < V_; ++v) yS[tid][v] = acc[v];
        }
        __syncthreads();
        const int nrow = (TC - tt0 < 256) ? (TC - tt0) : 256;
        const int n = nrow * V_;
        float* od = outb + (size_t)tt0 * V_;
        for (int i = tid; i < n; i += 512) {
            const int r = i / V_, v = i - r * V_;
            od[i] = yS[r][v];
        }
        __syncthreads();
    }
}

// ---------------- merged: gemm(c+1) [4*TC blocks] + proj(c) [B blocks] ----------------
__global__ __launch_bounds__(512, 2)
void gemm_proj(const float* __restrict__ h0buf,
               const float* __restrict__ wx1,
               const float* __restrict__ b1,
               float* __restrict__ xg1,
               const float* __restrict__ h1buf,
               const float* __restrict__ why,
               const float* __restrict__ by,
               float* __restrict__ out,
               int t0_proj, int TC, int gemmBlocks)
{
    __shared__ __align__(16) float smem[SMEMF];   // fits gemm aT AND proj bufs
    const int bid = blockIdx.x;
    if (bid < gemmBlocks) {
        gemm_body(threadIdx.x, bid, h0buf, wx1, b1, xg1, smem);
    } else {
        float (*whyS)[H_] = reinterpret_cast<float (*)[H_]>(smem);               // 3456
        float* byS        = smem + V_ * H_;                                       // 27
        float (*yS)[29]   = reinterpret_cast<float (*)[29]>(smem + V_ * H_ + 32); // 7424
        proj_body512(threadIdx.x, bid - gemmBlocks, h1buf, why, by, out,
                     t0_proj, TC, whyS, byS, yS);
    }
}

// ---------------- standalone gemm (fill) ----------------
__global__ __launch_bounds__(G4, 2)
void gemm_xg1(const float* __restrict__ h0buf,
              const float* __restrict__ wx1,
              const float* __restrict__ b1,
              float* __restrict__ xg1)
{
    __shared__ __align__(16) float aT[64 * 132];
    gemm_body(threadIdx.x, blockIdx.x, h0buf, wx1, b1, xg1, aT);
}

// ---------------- standalone proj (drain) ----------------
__global__ __launch_bounds__(512, 2)
void proj_y(const float* __restrict__ h1buf,
            const float* __restrict__ why,
            const float* __restrict__ by,
            float* __restrict__ out,
            int t0, int TC)
{
    __shared__ __align__(16) float smem[SMEMF];
    float (*whyS)[H_] = reinterpret_cast<float (*)[H_]>(smem);
    float* byS        = smem + V_ * H_;
    float (*yS)[29]   = reinterpret_cast<float (*)[29]>(smem + V_ * H_ + 32);
    proj_body512(threadIdx.x, blockIdx.x, h1buf, why, by, out, t0, TC,
                 whyS, byS, yS);
}

// ---------------- fallback: streaming kernel (uses [v][4][132] table) ----------------
__global__ __launch_bounds__(G4, 1)
void lstm_persist(const int* __restrict__ x,
                  const float* __restrict__ table0,
                  const float* __restrict__ wh0,
                  const float* __restrict__ wx1,
                  const float* __restrict__ wh1,
                  const float* __restrict__ b1,
                  const float* __restrict__ why,
                  const float* __restrict__ by,
                  float* __restrict__ out)
{
    const int j  = threadIdx.x;
    const int bb = blockIdx.x * 2;

    __shared__ float h0s[2][H_], c0s[2][H_], h1s[2][H_], c1s[2][H_];
    __shared__ float hcat[2][2 * H_];
    __shared__ float g0s[2][G4], g1s[2][G4];
    __shared__ float whyS[H_ * V_];
    __shared__ float b1S[G4];
    __shared__ float byS[V_];
    __shared__ float pb[2][V_][8];

    for (int i = j; i < H_ * V_; i += G4) whyS[i] = why[i];
    b1S[j] = b1[j];
    if (j < V_) byS[j] = by[j];
    if (j < H_) {
        h0s[0][j] = 0.f; h0s[1][j] = 0.f; c0s[0][j] = 0.f; c0s[1][j] = 0.f;
        h1s[0][j] = 0.f; h1s[1][j] = 0.f; c1s[0][j] = 0.f; c1s[1][j] = 0.f;
    }
    __syncthreads();

    const int* xA = x + (size_t)(bb + 0) * T_;
    const int* xB = x + (size_t)(bb + 1) * T_;
    float* outA = out + (size_t)(bb + 0) * T_ * V_;
    float* outB = out + (size_t)(bb + 1) * T_ * V_;

    const int tix = (j >> 7) * 132 + (j & (H_ - 1));

    for (int t = 0; t < T_; ++t) {
        const int ia = xA[t];
        const int ib = xB[t];
        float aA = table0[ia * TPITCH + tix];
        float aB = table0[ib * TPITCH + tix];
#pragma unroll 8
        for (int k = 0; k < H_; ++k) {
            const float w = wh0[k * G4 + j];
            aA += h0s[0][k] * w;
            aB += h0s[1][k] * w;
        }
        g0s[0][j] = aA; g0s[1][j] = aB;
        __syncthreads();

        if (j < 2 * H_) {
            const int gi = j >> 7, r = j & (H_ - 1);
            const float f  = 1.f / (1.f + expf(-g0s[gi][r]));
            const float i_ = 1.f / (1.f + expf(-g0s[gi][H_ + r]));
            const float g  = tanhf(g0s[gi][2 * H_ + r]);
            const float o  = 1.f / (1.f + expf(-g0s[gi][3 * H_ + r]));
            const float c  = f * c0s[gi][r] + i_ * g;
            c0s[gi][r] = c;
            const float h = tanhf(c) * o;
            h0s[gi][r] = h;
            hcat[gi][r] = h;
            hcat[gi][H_ + r] = h1s[gi][r];
        }
        __syncthreads();

        float bA = b1S[j];
        float bB = bA;
#pragma unroll 8
        for (int k = 0; k < H_; ++k) {
            const float w = wx1[k * G4 + j];
            bA += hcat[0][k] * w;
            bB += hcat[1][k] * w;
        }
#pragma unroll 8
        for (int k = 0; k < H_; ++k) {
            const float w = wh1[k * G4 + j];
            bA += hcat[0][H_ + k] * w;
            bB += hcat[1][H_ + k] * w;
        }
        g1s[0][j] = bA; g1s[1][j] = bB;
        __syncthreads();

        if (j < 2 * H_) {
            const int gi = j >> 7, r = j & (H_ - 1);
            const float f  = 1.f / (1.f + expf(-g1s[gi][r]));
            const float i_ = 1.f / (1.f + expf(-g1s[gi][H_ + r]));
            const float g  = tanhf(g1s[gi][2 * H_ + r]);
            const float o  = 1.f / (1.f + expf(-g1s[gi][3 * H_ + r]));
            const float c  = f * c1s[gi][r] + i_ * g;
            c1s[gi][r] = c;
            h1s[gi][r] = tanhf(c) * o;
        }
        __syncthreads();

        if (j < 2 * V_ * 8) {
            int qq = j;
            const int gi = (qq >= V_ * 8) ? 1 : 0;
            qq -= gi * V_ * 8;
            const int v = qq >> 3, kk = qq & 7;
            float pv = 0.f;
#pragma unroll
            for (int k = kk * 16; k < kk * 16 + 16; ++k)
                pv += h1s[gi][k] * whyS[k * V_ + v];
            pb[gi][v][kk] = pv;
        }
        __syncthreads();

        if (j < 2 * V_) {
            const int gi = (j >= V_) ? 1 : 0;
            const int v  = j - gi * V_;
            float sA = byS[v];
#pragma unroll
            for (int qq = 0; qq < 8; ++qq) sA += pb[gi][v][qq];
            (gi ? outB : outA)[t * V_ + v] = sA;
        }
        __syncthreads();
    }
}

// ---------------- host ----------------
extern "C" void kernel_launch(void* const* d_in, const int* in_sizes, int n_in,
                              void* d_out, int out_size, void* d_ws, size_t ws_size,
                              hipStream_t stream)
{
    const int*   x   = (const int*)  d_in[0];
    const float* emb = (const float*)d_in[1];
    const float* wx0 = (const float*)d_in[2];
    const float* wh0 = (const float*)d_in[3];
    const float* b0  = (const float*)d_in[4];
    const float* wx1 = (const float*)d_in[5];
    const float* wh1 = (const float*)d_in[6];
    const float* b1  = (const float*)d_in[7];
    const float* why = (const float*)d_in[8];
    const float* by  = (const float*)d_in[9];
    float* out = (float*)d_out;
    float* wsf = (float*)d_ws;

    const size_t tabF   = (size_t)V_ * TPITCH;   // 14256 floats
    const size_t stateF = (size_t)4 * B_ * H_;   // 131072 floats

    int TC = 0;
    for (int tc = 256; tc >= 32; tc >>= 1) {
        const size_t need = (tabF + stateF + (size_t)B_ * tc * (H_ + G4 + H_)) * 4;
        if (need <= ws_size) { TC = tc; break; }
    }

    float* table0 = wsf;
    build_table0<<<dim3(V_), dim3(G4), 0, stream>>>(emb, wx0, b0, table0);

    if (TC == 0) {
        lstm_persist<<<dim3(B_ / 2), dim3(G4), 0, stream>>>(
            x, table0, wh0, wx1, wh1, b1, why, by, out);
        return;
    }

    float* h0st   = wsf + tabF;
    float* c0st   = h0st + (size_t)B_ * H_;
    float* h1st   = c0st + (size_t)B_ * H_;
    float* c1st   = h1st + (size_t)B_ * H_;
    float* h0buf  = c1st + (size_t)B_ * H_;
    float* xg1buf = h0buf + (size_t)B_ * TC * H_;
    float* h1buf  = xg1buf + (size_t)B_ * TC * G4;

    (void)hipMemsetAsync(h0st, 0, stateF * sizeof(float), stream);

    const int NC = T_ / TC;
    const int gemmBlocks = 4 * TC;

    // fill: full-width single-batch l0 on chunk 0 + its gemm
    lstm_l0_1b<<<dim3(B_), dim3(512), 0, stream>>>(
        x, table0, wh0, h0st, c0st, h0buf, 0, TC);
    gemm_xg1<<<dim3(gemmBlocks), dim3(G4), 0, stream>>>(h0buf, wx1, b1, xg1buf);

    // pipelined middle: fused{l1(c) || l0(c+1)}; merged{gemm(c+1) || proj(c)}
    for (int c = 0; c < NC - 1; ++c) {
        lstm_fused2<<<dim3(B_), dim3(512), 0, stream>>>(
            x, table0, wh0, xg1buf, wh1,
            h0st, c0st, h0buf, h1st, c1st, h1buf,
            (c + 1) * TC, TC);
        gemm_proj<<<dim3(gemmBlocks + B_), dim3(512), 0, stream>>>(
            h0buf, wx1, b1, xg1buf,
            h1buf, why, by, out, c * TC, TC, gemmBlocks);
    }

    // drain: full-width single-batch l1 on last chunk + its proj
    lstm_l1_1b<<<dim3(B_), dim3(512), 0, stream>>>(
        xg1buf, wh1, h1st, c1st, h1buf, TC);
    proj_y<<<dim3(B_), dim3(512), 0, stream>>>(
        h1buf, why, by, out, (NC - 1) * TC, TC);
}